// Round 4
// baseline (2752.149 us; speedup 1.0000x reference)
//
#include <hip/hip_runtime.h>
#include <hip/hip_bf16.h>
#include <math.h>

#define Bdim 2
#define Tdim 1024
#define Cdim 1024
#define Hdim 16
#define Ndim 64
#define CCdim (Cdim * Cdim)
#define EPS_GN 0.00064f

typedef __bf16 bf8_t __attribute__((ext_vector_type(8)));
typedef float f32x4 __attribute__((ext_vector_type(4)));

static __device__ __forceinline__ float sigf(float x) { return 1.f / (1.f + expf(-x)); }

static __device__ __forceinline__ float wsum64(float v) {
    #pragma unroll
    for (int m = 1; m < 64; m <<= 1) v += __shfl_xor(v, m);
    return v;
}

static __device__ __forceinline__ void gload_lds16(const void* g, void* l) {
    __builtin_amdgcn_global_load_lds(
        (const __attribute__((address_space(1))) void*)g,
        (__attribute__((address_space(3))) void*)l, 16, 0, 0);
}

// ---------------------------------------------------------------------------
// Convert 4 weight matrices (C x C, row-major [n][k]) to bf16.
// ---------------------------------------------------------------------------
__global__ __launch_bounds__(256) void wconv_kernel(
    const float* __restrict__ W0, const float* __restrict__ W1,
    const float* __restrict__ W2, const float* __restrict__ W3,
    __hip_bfloat16* __restrict__ Wb)
{
    int blk = blockIdx.x;                 // 2048 blocks, 512 per matrix
    int which = blk >> 9;
    const float* src = (which == 0) ? W0 : (which == 1) ? W1 : (which == 2) ? W2 : W3;
    size_t e8 = ((size_t)(blk & 511) * 256 + threadIdx.x) * 8;
    float c[8];
    *(float4*)&c[0] = ((const float4*)(src + e8))[0];
    *(float4*)&c[4] = ((const float4*)(src + e8))[1];
    __hip_bfloat16 o[8];
    #pragma unroll
    for (int j = 0; j < 8; ++j) o[j] = __float2bfloat16(c[j]);
    __hip_bfloat16* dst = Wb + (size_t)which * CCdim + e8;
    ((ushort4*)dst)[0] = *(ushort4*)&o[0];
    ((ushort4*)dst)[1] = *(ushort4*)&o[4];
}

// ---------------------------------------------------------------------------
// Token-shift lerp for 3 mixes + bf16 convert: xr16, xk16, xv16.
// ---------------------------------------------------------------------------
__global__ __launch_bounds__(256) void prep_x(
    const float* __restrict__ xt,
    const float* __restrict__ mr, const float* __restrict__ mk, const float* __restrict__ mv,
    __hip_bfloat16* __restrict__ xr16, __hip_bfloat16* __restrict__ xk16,
    __hip_bfloat16* __restrict__ xv16)
{
    int idx8 = blockIdx.x * 256 + threadIdx.x;   // 0..262143
    int m = idx8 >> 7;
    int c8 = (idx8 & 127) * 8;
    int t = m & (Tdim - 1);
    const float* p = xt + (size_t)idx8 * 8;
    float cur[8], prv[8];
    *(float4*)&cur[0] = ((const float4*)p)[0];
    *(float4*)&cur[4] = ((const float4*)p)[1];
    if (t > 0) {
        *(float4*)&prv[0] = ((const float4*)(p - Cdim))[0];
        *(float4*)&prv[4] = ((const float4*)(p - Cdim))[1];
    } else {
        #pragma unroll
        for (int j = 0; j < 8; ++j) prv[j] = 0.f;
    }
    float mx[8];
    __hip_bfloat16 o[8];
    size_t ob = (size_t)idx8 * 8;

    *(float4*)&mx[0] = *(const float4*)(mr + c8);
    *(float4*)&mx[4] = *(const float4*)(mr + c8 + 4);
    #pragma unroll
    for (int j = 0; j < 8; ++j) o[j] = __float2bfloat16(cur[j] + (prv[j] - cur[j]) * mx[j]);
    ((ushort4*)(xr16 + ob))[0] = *(ushort4*)&o[0];
    ((ushort4*)(xr16 + ob))[1] = *(ushort4*)&o[4];

    *(float4*)&mx[0] = *(const float4*)(mk + c8);
    *(float4*)&mx[4] = *(const float4*)(mk + c8 + 4);
    #pragma unroll
    for (int j = 0; j < 8; ++j) o[j] = __float2bfloat16(cur[j] + (prv[j] - cur[j]) * mx[j]);
    ((ushort4*)(xk16 + ob))[0] = *(ushort4*)&o[0];
    ((ushort4*)(xk16 + ob))[1] = *(ushort4*)&o[4];

    *(float4*)&mx[0] = *(const float4*)(mv + c8);
    *(float4*)&mx[4] = *(const float4*)(mv + c8 + 4);
    #pragma unroll
    for (int j = 0; j < 8; ++j) o[j] = __float2bfloat16(cur[j] + (prv[j] - cur[j]) * mx[j]);
    ((ushort4*)(xv16 + ob))[0] = *(ushort4*)&o[0];
    ((ushort4*)(xv16 + ob))[1] = *(ushort4*)&o[4];
}

// ---------------------------------------------------------------------------
// bf16 MFMA GEMM: Cout[m][n] = sum_k A[m][k] * Bw[n][k], f32 out.
// 128x128 tile, BK=32, 256 thr (4 waves 2x2, each 64x64 via 4x4 16x16 frags).
// Staging via global_load_lds (16B), LDS [128][32] bf16 linear.
// ---------------------------------------------------------------------------
__global__ __launch_bounds__(256) void gemm_mfma(
    const __hip_bfloat16* __restrict__ A, const __hip_bfloat16* __restrict__ Bw,
    float* __restrict__ Cout, int M, int N, int K)
{
    __shared__ unsigned short At[128][32];
    __shared__ unsigned short Bt[128][32];
    int tid = threadIdx.x;
    int lane = tid & 63, wv = tid >> 6;
    int bm = blockIdx.y * 128, bn = blockIdx.x * 128;
    int wr = wv >> 1, wc = wv & 1;

    f32x4 acc[4][4];
    #pragma unroll
    for (int mi = 0; mi < 4; ++mi)
        #pragma unroll
        for (int ni = 0; ni < 4; ++ni)
            acc[mi][ni] = (f32x4){0.f, 0.f, 0.f, 0.f};

    int srow = wv * 16 + (lane >> 2);
    int scol = (lane & 3) * 8;
    const __hip_bfloat16* pa0 = A + (size_t)(bm + srow) * K + scol;
    const __hip_bfloat16* pa1 = A + (size_t)(bm + 64 + srow) * K + scol;
    const __hip_bfloat16* pb0 = Bw + (size_t)(bn + srow) * K + scol;
    const __hip_bfloat16* pb1 = Bw + (size_t)(bn + 64 + srow) * K + scol;
    char* At_b = (char*)&At[0][0] + wv * 1024;
    char* Bt_b = (char*)&Bt[0][0] + wv * 1024;

    for (int k0 = 0; k0 < K; k0 += 32) {
        gload_lds16(pa0 + k0, At_b);
        gload_lds16(pa1 + k0, At_b + 4096);
        gload_lds16(pb0 + k0, Bt_b);
        gload_lds16(pb1 + k0, Bt_b + 4096);
        __syncthreads();

        bf8_t af[4], bfr[4];
        #pragma unroll
        for (int mi = 0; mi < 4; ++mi)
            af[mi] = *(const bf8_t*)((const char*)&At[0][0] +
                     (wr * 64 + mi * 16 + (lane & 15)) * 64 + (lane >> 4) * 16);
        #pragma unroll
        for (int ni = 0; ni < 4; ++ni)
            bfr[ni] = *(const bf8_t*)((const char*)&Bt[0][0] +
                     (wc * 64 + ni * 16 + (lane & 15)) * 64 + (lane >> 4) * 16);
        #pragma unroll
        for (int mi = 0; mi < 4; ++mi)
            #pragma unroll
            for (int ni = 0; ni < 4; ++ni)
                acc[mi][ni] = __builtin_amdgcn_mfma_f32_16x16x32_bf16(
                    af[mi], bfr[ni], acc[mi][ni], 0, 0, 0);
        __syncthreads();
    }

    #pragma unroll
    for (int mi = 0; mi < 4; ++mi) {
        int r0 = bm + wr * 64 + mi * 16 + (lane >> 4) * 4;
        #pragma unroll
        for (int ni = 0; ni < 4; ++ni) {
            int c0 = bn + wc * 64 + ni * 16 + (lane & 15);
            #pragma unroll
            for (int j = 0; j < 4; ++j)
                Cout[(size_t)(r0 + j) * N + c0] = acc[mi][ni][j];
        }
    }
}

// ---------------------------------------------------------------------------
// Low-rank stage 1 (f32, unchanged)
// ---------------------------------------------------------------------------
__global__ __launch_bounds__(256) void lr1_kernel(
    const float* __restrict__ X, const float* __restrict__ mixv,
    const float* __restrict__ M1, float* __restrict__ Hout,
    int D, int act, int Tlen)
{
    __shared__ float row[Cdim];
    __shared__ float red[256];
    int m = blockIdx.x;
    int tid = threadIdx.x;
    int t = m % Tlen;
    const float* xr = X + (size_t)m * Cdim;
    #pragma unroll
    for (int q = 0; q < 4; ++q) {
        int kq = tid + q * 256;
        float v = xr[kq];
        float pv = (t > 0) ? xr[kq - Cdim] : 0.f;
        row[kq] = v + (pv - v) * mixv[kq];
    }
    __syncthreads();
    int P = 256 / D;
    int p = tid / D, n = tid % D;
    int klen = Cdim / P;
    float acc = 0.f;
    int kend = (p + 1) * klen;
    for (int k = p * klen; k < kend; ++k)
        acc += row[k] * M1[(size_t)k * D + n];
    red[tid] = acc;
    __syncthreads();
    if (tid < D) {
        float s = 0.f;
        for (int q = 0; q < P; ++q) s += red[tid + q * D];
        if (act == 1) s = sigf(s);
        else if (act == 2) s = tanhf(s);
        Hout[(size_t)m * D + tid] = s;
    }
}

// ---------------------------------------------------------------------------
// Low-rank stage 2. act: 0 none, 1 sigmoid, 3 sigmoid*e^-0.5.
// Writes f32 (OutF) or bf16 (OutB), whichever is non-null.
// ---------------------------------------------------------------------------
__global__ __launch_bounds__(256) void lr2_kernel(
    const float* __restrict__ Hin, const float* __restrict__ M2,
    const float* __restrict__ bias, float* __restrict__ OutF,
    __hip_bfloat16* __restrict__ OutB, int D, int act)
{
    __shared__ float hs[128];
    int m = blockIdx.y;
    int n = blockIdx.x * 256 + threadIdx.x;
    if (threadIdx.x < D) hs[threadIdx.x] = Hin[(size_t)m * D + threadIdx.x];
    __syncthreads();
    float acc = bias ? bias[n] : 0.f;
    for (int k = 0; k < D; ++k)
        acc += hs[k] * M2[(size_t)k * Cdim + n];
    if (act == 1) acc = sigf(acc);
    else if (act == 3) acc = sigf(acc) * 0.60653065971263342f;
    size_t oi = (size_t)m * Cdim + n;
    if (OutB) OutB[oi] = __float2bfloat16(acc);
    else OutF[oi] = acc;
}

// ---------------------------------------------------------------------------
// E1: kk-normalize -> aarr=-kkn, barr=kkn*at; ut; v_first passthrough.
// ---------------------------------------------------------------------------
__global__ __launch_bounds__(256) void e1_kernel(
    const float* __restrict__ kt, const __hip_bfloat16* __restrict__ at16,
    const float* __restrict__ rt, const float* __restrict__ vraw,
    const float* __restrict__ vt, const float* __restrict__ vfirst,
    const float* __restrict__ k_k, const float* __restrict__ k_a,
    const float* __restrict__ r_k,
    float* __restrict__ aarr, float* __restrict__ barr,
    float* __restrict__ ut, float* __restrict__ out2)
{
    int gid = blockIdx.x * 4 + (threadIdx.x >> 6);
    int lane = threadIdx.x & 63;
    int h = gid % Hdim;
    size_t idx = (size_t)gid * 64 + lane;
    int c = h * 64 + lane;
    float ktv = kt[idx];
    float atv = __bfloat162float(at16[idx]);
    float kk = ktv * k_k[c];
    float ss = wsum64(kk * kk);
    float norm = sqrtf(ss);
    float kkn = kk / fmaxf(norm, 1e-12f);
    aarr[idx] = -kkn;
    barr[idx] = kkn * atv;
    float kmix = ktv * (1.f + (atv - 1.f) * k_a[c]);
    float rv = rt[idx];
    float dot = wsum64(rv * kmix * r_k[c]);
    float vm = vraw[idx];
    float vf = vfirst[idx];
    vm = vm + (vf - vm) * vt[idx];
    ut[idx] = dot * vm;
    out2[idx] = vf;
}

// ---------------------------------------------------------------------------
// WKV scan: barrier-free, register double-buffered.
// Block = 512 thr = 2 (b,h) groups; per group 4 waves; wave owns 16 rows,
// 4 lanes/row (lane = i_loc*4+q owns cols [16q,16q+16)). All operands are
// per-lane global loads (L2-hit), prefetched one step ahead into registers.
// sa/out reduced via shfl_xor 1,2 (within-quad). No LDS, no barriers.
// ---------------------------------------------------------------------------
struct OpSet {
    float4 r[4], d[4], k[4], a[4], b[4];
    float v;
};

static __device__ __forceinline__ void wkv_load(
    OpSet& s, const float* pr, const float* pd, const float* pk,
    const float* pa, const float* pb, const float* pv, size_t o)
{
    #pragma unroll
    for (int c4 = 0; c4 < 4; ++c4) {
        s.r[c4] = *(const float4*)(pr + o + c4 * 4);
        s.d[c4] = *(const float4*)(pd + o + c4 * 4);
        s.k[c4] = *(const float4*)(pk + o + c4 * 4);
        s.a[c4] = *(const float4*)(pa + o + c4 * 4);
        s.b[c4] = *(const float4*)(pb + o + c4 * 4);
    }
    s.v = pv[o];
}

static __device__ __forceinline__ void wkv_step(
    float S[16], const OpSet& s, float* po, size_t o, int q)
{
    float sp = 0.f;
    #pragma unroll
    for (int c4 = 0; c4 < 4; ++c4) {
        sp += S[c4 * 4 + 0] * s.a[c4].x;
        sp += S[c4 * 4 + 1] * s.a[c4].y;
        sp += S[c4 * 4 + 2] * s.a[c4].z;
        sp += S[c4 * 4 + 3] * s.a[c4].w;
    }
    sp += __shfl_xor(sp, 1);
    sp += __shfl_xor(sp, 2);
    float op = 0.f;
    #pragma unroll
    for (int c4 = 0; c4 < 4; ++c4) {
        S[c4*4+0] = S[c4*4+0] * s.d[c4].x + (sp * s.b[c4].x + s.v * s.k[c4].x); op += S[c4*4+0] * s.r[c4].x;
        S[c4*4+1] = S[c4*4+1] * s.d[c4].y + (sp * s.b[c4].y + s.v * s.k[c4].y); op += S[c4*4+1] * s.r[c4].y;
        S[c4*4+2] = S[c4*4+2] * s.d[c4].z + (sp * s.b[c4].z + s.v * s.k[c4].z); op += S[c4*4+2] * s.r[c4].z;
        S[c4*4+3] = S[c4*4+3] * s.d[c4].w + (sp * s.b[c4].w + s.v * s.k[c4].w); op += S[c4*4+3] * s.r[c4].w;
    }
    op += __shfl_xor(op, 1);
    op += __shfl_xor(op, 2);
    if (q == 0) po[o] = op;
}

__global__ __launch_bounds__(512) void wkv_kernel(
    const float* rt, const float* decay, const float* kt, const float* vt,
    const float* aarr, const float* barr, float* wkvt)
{
    int tid = threadIdx.x;
    int wave = tid >> 6, lane = tid & 63;
    int g = wave >> 2, w = wave & 3;
    int bh = blockIdx.x * 2 + g;
    int b = bh >> 4, h = bh & 15;
    int i = w * 16 + (lane >> 2);
    int q = lane & 3;
    int jb = q * 16;
    size_t base = ((size_t)b * Tdim) * Cdim + (size_t)h * Ndim;
    const float* pr = rt + base + jb;
    const float* pd = decay + base + jb;
    const float* pk = kt + base + jb;
    const float* pa = aarr + base + jb;
    const float* pb = barr + base + jb;
    const float* pv = vt + base + i;
    float* po = wkvt + base + i;

    float S[16];
    #pragma unroll
    for (int j = 0; j < 16; ++j) S[j] = 0.f;

    OpSet sA, sB;
    wkv_load(sA, pr, pd, pk, pa, pb, pv, 0);
    for (int t = 0; t < Tdim; t += 2) {
        wkv_load(sB, pr, pd, pk, pa, pb, pv, (size_t)(t + 1) * Cdim);
        wkv_step(S, sA, po, (size_t)t * Cdim, q);
        int t2 = (t + 2 < Tdim) ? (t + 2) : (t + 1);
        wkv_load(sA, pr, pd, pk, pa, pb, pv, (size_t)t2 * Cdim);
        wkv_step(S, sB, po, (size_t)(t + 1) * Cdim, q);
    }
}

// ---------------------------------------------------------------------------
// E2: pt = GroupNorm(rt*wkvt)*ln_g + ln_b + ut; g16 = bf16(gt*pt)
// ---------------------------------------------------------------------------
__global__ __launch_bounds__(256) void e2_kernel(
    const float* __restrict__ rt, const float* __restrict__ wkvt,
    const float* __restrict__ ut, const __hip_bfloat16* __restrict__ gt16,
    const float* __restrict__ ln_g, const float* __restrict__ ln_b,
    __hip_bfloat16* __restrict__ g16)
{
    int gid = blockIdx.x * 4 + (threadIdx.x >> 6);
    int lane = threadIdx.x & 63;
    int h = gid % Hdim;
    size_t idx = (size_t)gid * 64 + lane;
    int c = h * 64 + lane;
    float x = rt[idx] * wkvt[idx];
    float mu = wsum64(x) * (1.f / 64.f);
    float d = x - mu;
    float var = wsum64(d * d) * (1.f / 64.f);
    float xn = d / sqrtf(var + EPS_GN);
    float pt = xn * ln_g[c] + ln_b[c] + ut[idx];
    float res = __bfloat162float(gt16[idx]) * pt;
    g16[idx] = __float2bfloat16(res);
}

// ---------------------------------------------------------------------------
extern "C" void kernel_launch(void* const* d_in, const int* in_sizes, int n_in,
                              void* d_out, int out_size, void* d_ws, size_t ws_size,
                              hipStream_t stream)
{
    (void)in_sizes; (void)n_in; (void)out_size; (void)ws_size;
    const float* xt      = (const float*)d_in[0];
    const float* v_first = (const float*)d_in[1];
    const float* tmix_r  = (const float*)d_in[2];
    const float* tmix_w  = (const float*)d_in[3];
    const float* tmix_k  = (const float*)d_in[4];
    const float* tmix_v  = (const float*)d_in[5];
    const float* tmix_a  = (const float*)d_in[6];
    const float* tmix_g  = (const float*)d_in[7];
    const float* w1 = (const float*)d_in[8];
    const float* w2 = (const float*)d_in[9];
    const float* w0 = (const float*)d_in[10];
    const float* a1 = (const float*)d_in[11];
    const float* a2 = (const float*)d_in[12];
    const float* a0 = (const float*)d_in[13];
    const float* v1 = (const float*)d_in[14];
    const float* v2 = (const float*)d_in[15];
    const float* v0 = (const float*)d_in[16];
    const float* g1 = (const float*)d_in[17];
    const float* g2 = (const float*)d_in[18];
    const float* k_k = (const float*)d_in[19];
    const float* k_a = (const float*)d_in[20];
    const float* r_k = (const float*)d_in[21];
    const float* W_r = (const float*)d_in[22];
    const float* W_k = (const float*)d_in[23];
    const float* W_v = (const float*)d_in[24];
    const float* W_o = (const float*)d_in[25];
    const float* ln_g = (const float*)d_in[26];
    const float* ln_b = (const float*)d_in[27];

    float* out = (float*)d_out;
    const size_t BTC = (size_t)Bdim * Tdim * Cdim;   // 2,097,152
    const int M = Bdim * Tdim;                        // 2048

    // ws layout (101 MB total):
    //  f32: rt kt vraw vt decay aarr barr ut wkv   (9 x 8 MB)
    //  bf16: at16 gt16 xr16 xk16 xv16(=g16) Wb[4xCC]  (28 MB)
    //  f32: hbuf (1 MB)
    float* ws = (float*)d_ws;
    float* rt    = ws + 0 * BTC;
    float* kt    = ws + 1 * BTC;
    float* vraw  = ws + 2 * BTC;
    float* vt    = ws + 3 * BTC;
    float* decay = ws + 4 * BTC;
    float* aarr  = ws + 5 * BTC;
    float* barr  = ws + 6 * BTC;
    float* ut    = ws + 7 * BTC;
    float* wkv   = ws + 8 * BTC;
    __hip_bfloat16* bfa = (__hip_bfloat16*)(ws + 9 * BTC);
    __hip_bfloat16* at16 = bfa + 0 * BTC;
    __hip_bfloat16* gt16 = bfa + 1 * BTC;
    __hip_bfloat16* xr16 = bfa + 2 * BTC;
    __hip_bfloat16* xk16 = bfa + 3 * BTC;
    __hip_bfloat16* xv16 = bfa + 4 * BTC;   // reused as g16 after gemm_v
    __hip_bfloat16* Wb   = bfa + 5 * BTC;   // 4*CCdim = 2*BTC bf16
    float* hbuf = (float*)(bfa + 7 * BTC);
    __hip_bfloat16* g16 = xv16;

    // prep: weights + lerped activations -> bf16
    wconv_kernel<<<2048, 256, 0, stream>>>(W_r, W_k, W_v, W_o, Wb);
    prep_x<<<1024, 256, 0, stream>>>(xt, tmix_r, tmix_k, tmix_v, xr16, xk16, xv16);

    // big projections (bf16 MFMA)
    dim3 gg(Cdim / 128, M / 128);   // (8,16)
    gemm_mfma<<<gg, 256, 0, stream>>>(xr16, Wb + 0 * (size_t)CCdim, rt,   M, Cdim, Cdim);
    gemm_mfma<<<gg, 256, 0, stream>>>(xk16, Wb + 1 * (size_t)CCdim, kt,   M, Cdim, Cdim);
    gemm_mfma<<<gg, 256, 0, stream>>>(xv16, Wb + 2 * (size_t)CCdim, vraw, M, Cdim, Cdim);

    // low-rank paths
    lr1_kernel<<<M, 256, 0, stream>>>(xt, tmix_w, w1, hbuf, 64, 2, Tdim);
    lr2_kernel<<<dim3(Cdim / 256, M), 256, 0, stream>>>(hbuf, w2, w0, decay, nullptr, 64, 3);
    lr1_kernel<<<M, 256, 0, stream>>>(xt, tmix_a, a1, hbuf, 64, 0, Tdim);
    lr2_kernel<<<dim3(Cdim / 256, M), 256, 0, stream>>>(hbuf, a2, a0, nullptr, at16, 64, 1);
    lr1_kernel<<<M, 256, 0, stream>>>(xt, tmix_v, v1, hbuf, 32, 0, Tdim);
    lr2_kernel<<<dim3(Cdim / 256, M), 256, 0, stream>>>(hbuf, v2, v0, vt, nullptr, 32, 1);
    lr1_kernel<<<M, 256, 0, stream>>>(xt, tmix_g, g1, hbuf, 128, 1, Tdim);
    lr2_kernel<<<dim3(Cdim / 256, M), 256, 0, stream>>>(hbuf, g2, nullptr, nullptr, gt16, 128, 0);

    // E1
    e1_kernel<<<(Bdim * Tdim * Hdim) / 4, 256, 0, stream>>>(
        kt, at16, rt, vraw, vt, v_first, k_k, k_a, r_k,
        aarr, barr, ut, out + BTC);

    // WKV scan (barrier-free, register-pipelined)
    wkv_kernel<<<(Bdim * Hdim) / 2, 512, 0, stream>>>(rt, decay, kt, vt, aarr, barr, wkv);

    // E2 (writes bf16 gated output)
    e2_kernel<<<(Bdim * Tdim * Hdim) / 4, 256, 0, stream>>>(
        rt, wkv, ut, gt16, ln_g, ln_b, g16);

    // output projection (bf16 MFMA)
    gemm_mfma<<<gg, 256, 0, stream>>>(g16, Wb + 3 * (size_t)CCdim, out, M, Cdim, Cdim);
}

// Round 5
// 2751.353 us; speedup vs baseline: 1.0003x; 1.0003x over previous
//
#include <hip/hip_runtime.h>
#include <hip/hip_bf16.h>
#include <math.h>

#define Bdim 2
#define Tdim 1024
#define Cdim 1024
#define Hdim 16
#define Ndim 64
#define CCdim (Cdim * Cdim)
#define EPS_GN 0.00064f

typedef __bf16 bf8_t __attribute__((ext_vector_type(8)));
typedef float f32x4 __attribute__((ext_vector_type(4)));

static __device__ __forceinline__ float sigf(float x) { return 1.f / (1.f + expf(-x)); }

static __device__ __forceinline__ float wsum64(float v) {
    #pragma unroll
    for (int m = 1; m < 64; m <<= 1) v += __shfl_xor(v, m);
    return v;
}

static __device__ __forceinline__ void gload_lds16(const void* g, void* l) {
    __builtin_amdgcn_global_load_lds(
        (const __attribute__((address_space(1))) void*)g,
        (__attribute__((address_space(3))) void*)l, 16, 0, 0);
}

// ---------------------------------------------------------------------------
// Convert 4 weight matrices (C x C, row-major [n][k]) to bf16.
// ---------------------------------------------------------------------------
__global__ __launch_bounds__(256) void wconv_kernel(
    const float* __restrict__ W0, const float* __restrict__ W1,
    const float* __restrict__ W2, const float* __restrict__ W3,
    __hip_bfloat16* __restrict__ Wb)
{
    int blk = blockIdx.x;                 // 2048 blocks, 512 per matrix
    int which = blk >> 9;
    const float* src = (which == 0) ? W0 : (which == 1) ? W1 : (which == 2) ? W2 : W3;
    size_t e8 = ((size_t)(blk & 511) * 256 + threadIdx.x) * 8;
    float c[8];
    *(float4*)&c[0] = ((const float4*)(src + e8))[0];
    *(float4*)&c[4] = ((const float4*)(src + e8))[1];
    __hip_bfloat16 o[8];
    #pragma unroll
    for (int j = 0; j < 8; ++j) o[j] = __float2bfloat16(c[j]);
    __hip_bfloat16* dst = Wb + (size_t)which * CCdim + e8;
    ((ushort4*)dst)[0] = *(ushort4*)&o[0];
    ((ushort4*)dst)[1] = *(ushort4*)&o[4];
}

// ---------------------------------------------------------------------------
// Token-shift lerp for 3 mixes + bf16 convert: xr16, xk16, xv16.
// ---------------------------------------------------------------------------
__global__ __launch_bounds__(256) void prep_x(
    const float* __restrict__ xt,
    const float* __restrict__ mr, const float* __restrict__ mk, const float* __restrict__ mv,
    __hip_bfloat16* __restrict__ xr16, __hip_bfloat16* __restrict__ xk16,
    __hip_bfloat16* __restrict__ xv16)
{
    int idx8 = blockIdx.x * 256 + threadIdx.x;   // 0..262143
    int m = idx8 >> 7;
    int c8 = (idx8 & 127) * 8;
    int t = m & (Tdim - 1);
    const float* p = xt + (size_t)idx8 * 8;
    float cur[8], prv[8];
    *(float4*)&cur[0] = ((const float4*)p)[0];
    *(float4*)&cur[4] = ((const float4*)p)[1];
    if (t > 0) {
        *(float4*)&prv[0] = ((const float4*)(p - Cdim))[0];
        *(float4*)&prv[4] = ((const float4*)(p - Cdim))[1];
    } else {
        #pragma unroll
        for (int j = 0; j < 8; ++j) prv[j] = 0.f;
    }
    float mx[8];
    __hip_bfloat16 o[8];
    size_t ob = (size_t)idx8 * 8;

    *(float4*)&mx[0] = *(const float4*)(mr + c8);
    *(float4*)&mx[4] = *(const float4*)(mr + c8 + 4);
    #pragma unroll
    for (int j = 0; j < 8; ++j) o[j] = __float2bfloat16(cur[j] + (prv[j] - cur[j]) * mx[j]);
    ((ushort4*)(xr16 + ob))[0] = *(ushort4*)&o[0];
    ((ushort4*)(xr16 + ob))[1] = *(ushort4*)&o[4];

    *(float4*)&mx[0] = *(const float4*)(mk + c8);
    *(float4*)&mx[4] = *(const float4*)(mk + c8 + 4);
    #pragma unroll
    for (int j = 0; j < 8; ++j) o[j] = __float2bfloat16(cur[j] + (prv[j] - cur[j]) * mx[j]);
    ((ushort4*)(xk16 + ob))[0] = *(ushort4*)&o[0];
    ((ushort4*)(xk16 + ob))[1] = *(ushort4*)&o[4];

    *(float4*)&mx[0] = *(const float4*)(mv + c8);
    *(float4*)&mx[4] = *(const float4*)(mv + c8 + 4);
    #pragma unroll
    for (int j = 0; j < 8; ++j) o[j] = __float2bfloat16(cur[j] + (prv[j] - cur[j]) * mx[j]);
    ((ushort4*)(xv16 + ob))[0] = *(ushort4*)&o[0];
    ((ushort4*)(xv16 + ob))[1] = *(ushort4*)&o[4];
}

// ---------------------------------------------------------------------------
// bf16 MFMA GEMM: Cout[m][n] = sum_k A[m][k] * Bw[n][k], f32 out.
// 128x128 tile, BK=32, 256 thr (4 waves 2x2, each 64x64 via 4x4 16x16 frags).
// ---------------------------------------------------------------------------
__global__ __launch_bounds__(256) void gemm_mfma(
    const __hip_bfloat16* __restrict__ A, const __hip_bfloat16* __restrict__ Bw,
    float* __restrict__ Cout, int M, int N, int K)
{
    __shared__ unsigned short At[128][32];
    __shared__ unsigned short Bt[128][32];
    int tid = threadIdx.x;
    int lane = tid & 63, wv = tid >> 6;
    int bm = blockIdx.y * 128, bn = blockIdx.x * 128;
    int wr = wv >> 1, wc = wv & 1;

    f32x4 acc[4][4];
    #pragma unroll
    for (int mi = 0; mi < 4; ++mi)
        #pragma unroll
        for (int ni = 0; ni < 4; ++ni)
            acc[mi][ni] = (f32x4){0.f, 0.f, 0.f, 0.f};

    int srow = wv * 16 + (lane >> 2);
    int scol = (lane & 3) * 8;
    const __hip_bfloat16* pa0 = A + (size_t)(bm + srow) * K + scol;
    const __hip_bfloat16* pa1 = A + (size_t)(bm + 64 + srow) * K + scol;
    const __hip_bfloat16* pb0 = Bw + (size_t)(bn + srow) * K + scol;
    const __hip_bfloat16* pb1 = Bw + (size_t)(bn + 64 + srow) * K + scol;
    char* At_b = (char*)&At[0][0] + wv * 1024;
    char* Bt_b = (char*)&Bt[0][0] + wv * 1024;

    for (int k0 = 0; k0 < K; k0 += 32) {
        gload_lds16(pa0 + k0, At_b);
        gload_lds16(pa1 + k0, At_b + 4096);
        gload_lds16(pb0 + k0, Bt_b);
        gload_lds16(pb1 + k0, Bt_b + 4096);
        __syncthreads();

        bf8_t af[4], bfr[4];
        #pragma unroll
        for (int mi = 0; mi < 4; ++mi)
            af[mi] = *(const bf8_t*)((const char*)&At[0][0] +
                     (wr * 64 + mi * 16 + (lane & 15)) * 64 + (lane >> 4) * 16);
        #pragma unroll
        for (int ni = 0; ni < 4; ++ni)
            bfr[ni] = *(const bf8_t*)((const char*)&Bt[0][0] +
                     (wc * 64 + ni * 16 + (lane & 15)) * 64 + (lane >> 4) * 16);
        #pragma unroll
        for (int mi = 0; mi < 4; ++mi)
            #pragma unroll
            for (int ni = 0; ni < 4; ++ni)
                acc[mi][ni] = __builtin_amdgcn_mfma_f32_16x16x32_bf16(
                    af[mi], bfr[ni], acc[mi][ni], 0, 0, 0);
        __syncthreads();
    }

    #pragma unroll
    for (int mi = 0; mi < 4; ++mi) {
        int r0 = bm + wr * 64 + mi * 16 + (lane >> 4) * 4;
        #pragma unroll
        for (int ni = 0; ni < 4; ++ni) {
            int c0 = bn + wc * 64 + ni * 16 + (lane & 15);
            #pragma unroll
            for (int j = 0; j < 4; ++j)
                Cout[(size_t)(r0 + j) * N + c0] = acc[mi][ni][j];
        }
    }
}

// ---------------------------------------------------------------------------
// Low-rank stage 1 (f32)
// ---------------------------------------------------------------------------
__global__ __launch_bounds__(256) void lr1_kernel(
    const float* __restrict__ X, const float* __restrict__ mixv,
    const float* __restrict__ M1, float* __restrict__ Hout,
    int D, int act, int Tlen)
{
    __shared__ float row[Cdim];
    __shared__ float red[256];
    int m = blockIdx.x;
    int tid = threadIdx.x;
    int t = m % Tlen;
    const float* xr = X + (size_t)m * Cdim;
    #pragma unroll
    for (int q = 0; q < 4; ++q) {
        int kq = tid + q * 256;
        float v = xr[kq];
        float pv = (t > 0) ? xr[kq - Cdim] : 0.f;
        row[kq] = v + (pv - v) * mixv[kq];
    }
    __syncthreads();
    int P = 256 / D;
    int p = tid / D, n = tid % D;
    int klen = Cdim / P;
    float acc = 0.f;
    int kend = (p + 1) * klen;
    for (int k = p * klen; k < kend; ++k)
        acc += row[k] * M1[(size_t)k * D + n];
    red[tid] = acc;
    __syncthreads();
    if (tid < D) {
        float s = 0.f;
        for (int q = 0; q < P; ++q) s += red[tid + q * D];
        if (act == 1) s = sigf(s);
        else if (act == 2) s = tanhf(s);
        Hout[(size_t)m * D + tid] = s;
    }
}

// ---------------------------------------------------------------------------
// Low-rank stage 2. act: 0 none, 1 sigmoid, 3 sigmoid*e^-0.5.
// ---------------------------------------------------------------------------
__global__ __launch_bounds__(256) void lr2_kernel(
    const float* __restrict__ Hin, const float* __restrict__ M2,
    const float* __restrict__ bias, float* __restrict__ OutF,
    __hip_bfloat16* __restrict__ OutB, int D, int act)
{
    __shared__ float hs[128];
    int m = blockIdx.y;
    int n = blockIdx.x * 256 + threadIdx.x;
    if (threadIdx.x < D) hs[threadIdx.x] = Hin[(size_t)m * D + threadIdx.x];
    __syncthreads();
    float acc = bias ? bias[n] : 0.f;
    for (int k = 0; k < D; ++k)
        acc += hs[k] * M2[(size_t)k * Cdim + n];
    if (act == 1) acc = sigf(acc);
    else if (act == 3) acc = sigf(acc) * 0.60653065971263342f;
    size_t oi = (size_t)m * Cdim + n;
    if (OutB) OutB[oi] = __float2bfloat16(acc);
    else OutF[oi] = acc;
}

// ---------------------------------------------------------------------------
// E1: kk-normalize -> aarr=-kkn, barr=kkn*at; ut; v_first passthrough.
// ---------------------------------------------------------------------------
__global__ __launch_bounds__(256) void e1_kernel(
    const float* __restrict__ kt, const __hip_bfloat16* __restrict__ at16,
    const float* __restrict__ rt, const float* __restrict__ vraw,
    const float* __restrict__ vt, const float* __restrict__ vfirst,
    const float* __restrict__ k_k, const float* __restrict__ k_a,
    const float* __restrict__ r_k,
    float* __restrict__ aarr, float* __restrict__ barr,
    float* __restrict__ ut, float* __restrict__ out2)
{
    int gid = blockIdx.x * 4 + (threadIdx.x >> 6);
    int lane = threadIdx.x & 63;
    int h = gid % Hdim;
    size_t idx = (size_t)gid * 64 + lane;
    int c = h * 64 + lane;
    float ktv = kt[idx];
    float atv = __bfloat162float(at16[idx]);
    float kk = ktv * k_k[c];
    float ss = wsum64(kk * kk);
    float norm = sqrtf(ss);
    float kkn = kk / fmaxf(norm, 1e-12f);
    aarr[idx] = -kkn;
    barr[idx] = kkn * atv;
    float kmix = ktv * (1.f + (atv - 1.f) * k_a[c]);
    float rv = rt[idx];
    float dot = wsum64(rv * kmix * r_k[c]);
    float vm = vraw[idx];
    float vf = vfirst[idx];
    vm = vm + (vf - vm) * vt[idx];
    ut[idx] = dot * vm;
    out2[idx] = vf;
}

// ---------------------------------------------------------------------------
// WKV scan: barrier-free, SINGLE-buffered per-lane operand registers.
// Block = 512 thr = 2 (b,h) groups; per group 4 waves; wave owns 16 rows,
// 4 lanes/row (lane = i_loc*4+q owns cols [16q,16q+16)). Per step: batch-
// issue 21 loads (a first, r last), one latency wait, ~110 VALU compute.
// Live set ~120 VGPR -> no demotion (R3 failure was 2x81-reg double buffer
// vs 108-VGPR cap => serialized L2 round-trips).
// ---------------------------------------------------------------------------
__global__ __launch_bounds__(512, 2) void wkv_kernel(
    const float* __restrict__ rt, const float* __restrict__ decay,
    const float* __restrict__ kt, const float* __restrict__ vt,
    const float* __restrict__ aarr, const float* __restrict__ barr,
    float* __restrict__ wkvt)
{
    int tid = threadIdx.x;
    int wave = tid >> 6, lane = tid & 63;
    int g = wave >> 2, w = wave & 3;
    int bh = blockIdx.x * 2 + g;
    int b = bh >> 4, h = bh & 15;
    int i = w * 16 + (lane >> 2);
    int q = lane & 3;
    int jb = q * 16;
    size_t base = ((size_t)b * Tdim) * Cdim + (size_t)h * Ndim;
    const float* pa = aarr + base + jb;
    const float* pv = vt + base + i;
    const float* pd = decay + base + jb;
    const float* pk = kt + base + jb;
    const float* pb = barr + base + jb;
    const float* pr = rt + base + jb;
    float* po = wkvt + base + i;

    float S[16];
    #pragma unroll
    for (int j = 0; j < 16; ++j) S[j] = 0.f;

    for (int t = 0; t < Tdim; ++t) {
        // batch-issue all operand loads; order = use order
        float4 a4[4], d4[4], k4[4], b4[4], r4[4];
        float vi;
        #pragma unroll
        for (int c4 = 0; c4 < 4; ++c4) a4[c4] = *(const float4*)(pa + c4 * 4);
        vi = *pv;
        #pragma unroll
        for (int c4 = 0; c4 < 4; ++c4) d4[c4] = *(const float4*)(pd + c4 * 4);
        #pragma unroll
        for (int c4 = 0; c4 < 4; ++c4) k4[c4] = *(const float4*)(pk + c4 * 4);
        #pragma unroll
        for (int c4 = 0; c4 < 4; ++c4) b4[c4] = *(const float4*)(pb + c4 * 4);
        #pragma unroll
        for (int c4 = 0; c4 < 4; ++c4) r4[c4] = *(const float4*)(pr + c4 * 4);

        float sp = 0.f;
        #pragma unroll
        for (int c4 = 0; c4 < 4; ++c4) {
            sp += S[c4 * 4 + 0] * a4[c4].x;
            sp += S[c4 * 4 + 1] * a4[c4].y;
            sp += S[c4 * 4 + 2] * a4[c4].z;
            sp += S[c4 * 4 + 3] * a4[c4].w;
        }
        sp += __shfl_xor(sp, 1);
        sp += __shfl_xor(sp, 2);

        float op = 0.f;
        #pragma unroll
        for (int c4 = 0; c4 < 4; ++c4) {
            S[c4*4+0] = S[c4*4+0] * d4[c4].x + (sp * b4[c4].x + vi * k4[c4].x); op += S[c4*4+0] * r4[c4].x;
            S[c4*4+1] = S[c4*4+1] * d4[c4].y + (sp * b4[c4].y + vi * k4[c4].y); op += S[c4*4+1] * r4[c4].y;
            S[c4*4+2] = S[c4*4+2] * d4[c4].z + (sp * b4[c4].z + vi * k4[c4].z); op += S[c4*4+2] * r4[c4].z;
            S[c4*4+3] = S[c4*4+3] * d4[c4].w + (sp * b4[c4].w + vi * k4[c4].w); op += S[c4*4+3] * r4[c4].w;
        }
        op += __shfl_xor(op, 1);
        op += __shfl_xor(op, 2);
        if (q == 0) *po = op;

        pa += Cdim; pv += Cdim; pd += Cdim; pk += Cdim;
        pb += Cdim; pr += Cdim; po += Cdim;
    }
}

// ---------------------------------------------------------------------------
// E2: pt = GroupNorm(rt*wkvt)*ln_g + ln_b + ut; g16 = bf16(gt*pt)
// ---------------------------------------------------------------------------
__global__ __launch_bounds__(256) void e2_kernel(
    const float* __restrict__ rt, const float* __restrict__ wkvt,
    const float* __restrict__ ut, const __hip_bfloat16* __restrict__ gt16,
    const float* __restrict__ ln_g, const float* __restrict__ ln_b,
    __hip_bfloat16* __restrict__ g16)
{
    int gid = blockIdx.x * 4 + (threadIdx.x >> 6);
    int lane = threadIdx.x & 63;
    int h = gid % Hdim;
    size_t idx = (size_t)gid * 64 + lane;
    int c = h * 64 + lane;
    float x = rt[idx] * wkvt[idx];
    float mu = wsum64(x) * (1.f / 64.f);
    float d = x - mu;
    float var = wsum64(d * d) * (1.f / 64.f);
    float xn = d / sqrtf(var + EPS_GN);
    float pt = xn * ln_g[c] + ln_b[c] + ut[idx];
    float res = __bfloat162float(gt16[idx]) * pt;
    g16[idx] = __float2bfloat16(res);
}

// ---------------------------------------------------------------------------
extern "C" void kernel_launch(void* const* d_in, const int* in_sizes, int n_in,
                              void* d_out, int out_size, void* d_ws, size_t ws_size,
                              hipStream_t stream)
{
    (void)in_sizes; (void)n_in; (void)out_size; (void)ws_size;
    const float* xt      = (const float*)d_in[0];
    const float* v_first = (const float*)d_in[1];
    const float* tmix_r  = (const float*)d_in[2];
    const float* tmix_w  = (const float*)d_in[3];
    const float* tmix_k  = (const float*)d_in[4];
    const float* tmix_v  = (const float*)d_in[5];
    const float* tmix_a  = (const float*)d_in[6];
    const float* tmix_g  = (const float*)d_in[7];
    const float* w1 = (const float*)d_in[8];
    const float* w2 = (const float*)d_in[9];
    const float* w0 = (const float*)d_in[10];
    const float* a1 = (const float*)d_in[11];
    const float* a2 = (const float*)d_in[12];
    const float* a0 = (const float*)d_in[13];
    const float* v1 = (const float*)d_in[14];
    const float* v2 = (const float*)d_in[15];
    const float* v0 = (const float*)d_in[16];
    const float* g1 = (const float*)d_in[17];
    const float* g2 = (const float*)d_in[18];
    const float* k_k = (const float*)d_in[19];
    const float* k_a = (const float*)d_in[20];
    const float* r_k = (const float*)d_in[21];
    const float* W_r = (const float*)d_in[22];
    const float* W_k = (const float*)d_in[23];
    const float* W_v = (const float*)d_in[24];
    const float* W_o = (const float*)d_in[25];
    const float* ln_g = (const float*)d_in[26];
    const float* ln_b = (const float*)d_in[27];

    float* out = (float*)d_out;
    const size_t BTC = (size_t)Bdim * Tdim * Cdim;   // 2,097,152
    const int M = Bdim * Tdim;                        // 2048

    float* ws = (float*)d_ws;
    float* rt    = ws + 0 * BTC;
    float* kt    = ws + 1 * BTC;
    float* vraw  = ws + 2 * BTC;
    float* vt    = ws + 3 * BTC;
    float* decay = ws + 4 * BTC;
    float* aarr  = ws + 5 * BTC;
    float* barr  = ws + 6 * BTC;
    float* ut    = ws + 7 * BTC;
    float* wkv   = ws + 8 * BTC;
    __hip_bfloat16* bfa = (__hip_bfloat16*)(ws + 9 * BTC);
    __hip_bfloat16* at16 = bfa + 0 * BTC;
    __hip_bfloat16* gt16 = bfa + 1 * BTC;
    __hip_bfloat16* xr16 = bfa + 2 * BTC;
    __hip_bfloat16* xk16 = bfa + 3 * BTC;
    __hip_bfloat16* xv16 = bfa + 4 * BTC;   // reused as g16 after gemm_v
    __hip_bfloat16* Wb   = bfa + 5 * BTC;   // 4*CCdim = 2*BTC bf16
    float* hbuf = (float*)(bfa + 7 * BTC);
    __hip_bfloat16* g16 = xv16;

    // prep: weights + lerped activations -> bf16
    wconv_kernel<<<2048, 256, 0, stream>>>(W_r, W_k, W_v, W_o, Wb);
    prep_x<<<1024, 256, 0, stream>>>(xt, tmix_r, tmix_k, tmix_v, xr16, xk16, xv16);

    // big projections (bf16 MFMA)
    dim3 gg(Cdim / 128, M / 128);   // (8,16)
    gemm_mfma<<<gg, 256, 0, stream>>>(xr16, Wb + 0 * (size_t)CCdim, rt,   M, Cdim, Cdim);
    gemm_mfma<<<gg, 256, 0, stream>>>(xk16, Wb + 1 * (size_t)CCdim, kt,   M, Cdim, Cdim);
    gemm_mfma<<<gg, 256, 0, stream>>>(xv16, Wb + 2 * (size_t)CCdim, vraw, M, Cdim, Cdim);

    // low-rank paths
    lr1_kernel<<<M, 256, 0, stream>>>(xt, tmix_w, w1, hbuf, 64, 2, Tdim);
    lr2_kernel<<<dim3(Cdim / 256, M), 256, 0, stream>>>(hbuf, w2, w0, decay, nullptr, 64, 3);
    lr1_kernel<<<M, 256, 0, stream>>>(xt, tmix_a, a1, hbuf, 64, 0, Tdim);
    lr2_kernel<<<dim3(Cdim / 256, M), 256, 0, stream>>>(hbuf, a2, a0, nullptr, at16, 64, 1);
    lr1_kernel<<<M, 256, 0, stream>>>(xt, tmix_v, v1, hbuf, 32, 0, Tdim);
    lr2_kernel<<<dim3(Cdim / 256, M), 256, 0, stream>>>(hbuf, v2, v0, vt, nullptr, 32, 1);
    lr1_kernel<<<M, 256, 0, stream>>>(xt, tmix_g, g1, hbuf, 128, 1, Tdim);
    lr2_kernel<<<dim3(Cdim / 256, M), 256, 0, stream>>>(hbuf, g2, nullptr, nullptr, gt16, 128, 0);

    // E1
    e1_kernel<<<(Bdim * Tdim * Hdim) / 4, 256, 0, stream>>>(
        kt, at16, rt, vraw, vt, v_first, k_k, k_a, r_k,
        aarr, barr, ut, out + BTC);

    // WKV scan (barrier-free, single-buffered registers)
    wkv_kernel<<<(Bdim * Hdim) / 2, 512, 0, stream>>>(rt, decay, kt, vt, aarr, barr, wkv);

    // E2 (writes bf16 gated output)
    e2_kernel<<<(Bdim * Tdim * Hdim) / 4, 256, 0, stream>>>(
        rt, wkv, ut, gt16, ln_g, ln_b, g16);

    // output projection (bf16 MFMA)
    gemm_mfma<<<gg, 256, 0, stream>>>(g16, Wb + 3 * (size_t)CCdim, out, M, Cdim, Cdim);
}

// Round 6
// 2750.303 us; speedup vs baseline: 1.0007x; 1.0004x over previous
//
#include <hip/hip_runtime.h>
#include <hip/hip_bf16.h>
#include <math.h>

#define Bdim 2
#define Tdim 1024
#define Cdim 1024
#define Hdim 16
#define Ndim 64
#define CCdim (Cdim * Cdim)
#define EPS_GN 0.00064f

typedef __bf16 bf8_t __attribute__((ext_vector_type(8)));
typedef float f32x4 __attribute__((ext_vector_type(4)));
typedef float f4 __attribute__((ext_vector_type(4)));

static __device__ __forceinline__ float sigf(float x) { return 1.f / (1.f + expf(-x)); }

static __device__ __forceinline__ float wsum64(float v) {
    #pragma unroll
    for (int m = 1; m < 64; m <<= 1) v += __shfl_xor(v, m);
    return v;
}

static __device__ __forceinline__ void gload_lds16(const void* g, void* l) {
    __builtin_amdgcn_global_load_lds(
        (const __attribute__((address_space(1))) void*)g,
        (__attribute__((address_space(3))) void*)l, 16, 0, 0);
}

// quad (4-lane) reduce via DPP quad_perm: xor1 then xor2, VALU-speed.
static __device__ __forceinline__ float quad_reduce(float x) {
    int s1 = __builtin_amdgcn_update_dpp(0, __builtin_bit_cast(int, x),
                                         0xB1, 0xF, 0xF, true);   // [1,0,3,2]
    float y = x + __builtin_bit_cast(float, s1);
    int s2 = __builtin_amdgcn_update_dpp(0, __builtin_bit_cast(int, y),
                                         0x4E, 0xF, 0xF, true);   // [2,3,0,1]
    return y + __builtin_bit_cast(float, s2);
}

// ---------------------------------------------------------------------------
// Convert 4 weight matrices (C x C, row-major [n][k]) to bf16.
// ---------------------------------------------------------------------------
__global__ __launch_bounds__(256) void wconv_kernel(
    const float* __restrict__ W0, const float* __restrict__ W1,
    const float* __restrict__ W2, const float* __restrict__ W3,
    __hip_bfloat16* __restrict__ Wb)
{
    int blk = blockIdx.x;                 // 2048 blocks, 512 per matrix
    int which = blk >> 9;
    const float* src = (which == 0) ? W0 : (which == 1) ? W1 : (which == 2) ? W2 : W3;
    size_t e8 = ((size_t)(blk & 511) * 256 + threadIdx.x) * 8;
    float c[8];
    *(float4*)&c[0] = ((const float4*)(src + e8))[0];
    *(float4*)&c[4] = ((const float4*)(src + e8))[1];
    __hip_bfloat16 o[8];
    #pragma unroll
    for (int j = 0; j < 8; ++j) o[j] = __float2bfloat16(c[j]);
    __hip_bfloat16* dst = Wb + (size_t)which * CCdim + e8;
    ((ushort4*)dst)[0] = *(ushort4*)&o[0];
    ((ushort4*)dst)[1] = *(ushort4*)&o[4];
}

// ---------------------------------------------------------------------------
// Token-shift lerp for 3 mixes + bf16 convert: xr16, xk16, xv16.
// ---------------------------------------------------------------------------
__global__ __launch_bounds__(256) void prep_x(
    const float* __restrict__ xt,
    const float* __restrict__ mr, const float* __restrict__ mk, const float* __restrict__ mv,
    __hip_bfloat16* __restrict__ xr16, __hip_bfloat16* __restrict__ xk16,
    __hip_bfloat16* __restrict__ xv16)
{
    int idx8 = blockIdx.x * 256 + threadIdx.x;   // 0..262143
    int m = idx8 >> 7;
    int c8 = (idx8 & 127) * 8;
    int t = m & (Tdim - 1);
    const float* p = xt + (size_t)idx8 * 8;
    float cur[8], prv[8];
    *(float4*)&cur[0] = ((const float4*)p)[0];
    *(float4*)&cur[4] = ((const float4*)p)[1];
    if (t > 0) {
        *(float4*)&prv[0] = ((const float4*)(p - Cdim))[0];
        *(float4*)&prv[4] = ((const float4*)(p - Cdim))[1];
    } else {
        #pragma unroll
        for (int j = 0; j < 8; ++j) prv[j] = 0.f;
    }
    float mx[8];
    __hip_bfloat16 o[8];
    size_t ob = (size_t)idx8 * 8;

    *(float4*)&mx[0] = *(const float4*)(mr + c8);
    *(float4*)&mx[4] = *(const float4*)(mr + c8 + 4);
    #pragma unroll
    for (int j = 0; j < 8; ++j) o[j] = __float2bfloat16(cur[j] + (prv[j] - cur[j]) * mx[j]);
    ((ushort4*)(xr16 + ob))[0] = *(ushort4*)&o[0];
    ((ushort4*)(xr16 + ob))[1] = *(ushort4*)&o[4];

    *(float4*)&mx[0] = *(const float4*)(mk + c8);
    *(float4*)&mx[4] = *(const float4*)(mk + c8 + 4);
    #pragma unroll
    for (int j = 0; j < 8; ++j) o[j] = __float2bfloat16(cur[j] + (prv[j] - cur[j]) * mx[j]);
    ((ushort4*)(xk16 + ob))[0] = *(ushort4*)&o[0];
    ((ushort4*)(xk16 + ob))[1] = *(ushort4*)&o[4];

    *(float4*)&mx[0] = *(const float4*)(mv + c8);
    *(float4*)&mx[4] = *(const float4*)(mv + c8 + 4);
    #pragma unroll
    for (int j = 0; j < 8; ++j) o[j] = __float2bfloat16(cur[j] + (prv[j] - cur[j]) * mx[j]);
    ((ushort4*)(xv16 + ob))[0] = *(ushort4*)&o[0];
    ((ushort4*)(xv16 + ob))[1] = *(ushort4*)&o[4];
}

// ---------------------------------------------------------------------------
// bf16 MFMA GEMM: Cout[m][n] = sum_k A[m][k] * Bw[n][k], f32 out.
// ---------------------------------------------------------------------------
__global__ __launch_bounds__(256) void gemm_mfma(
    const __hip_bfloat16* __restrict__ A, const __hip_bfloat16* __restrict__ Bw,
    float* __restrict__ Cout, int M, int N, int K)
{
    __shared__ unsigned short At[128][32];
    __shared__ unsigned short Bt[128][32];
    int tid = threadIdx.x;
    int lane = tid & 63, wv = tid >> 6;
    int bm = blockIdx.y * 128, bn = blockIdx.x * 128;
    int wr = wv >> 1, wc = wv & 1;

    f32x4 acc[4][4];
    #pragma unroll
    for (int mi = 0; mi < 4; ++mi)
        #pragma unroll
        for (int ni = 0; ni < 4; ++ni)
            acc[mi][ni] = (f32x4){0.f, 0.f, 0.f, 0.f};

    int srow = wv * 16 + (lane >> 2);
    int scol = (lane & 3) * 8;
    const __hip_bfloat16* pa0 = A + (size_t)(bm + srow) * K + scol;
    const __hip_bfloat16* pa1 = A + (size_t)(bm + 64 + srow) * K + scol;
    const __hip_bfloat16* pb0 = Bw + (size_t)(bn + srow) * K + scol;
    const __hip_bfloat16* pb1 = Bw + (size_t)(bn + 64 + srow) * K + scol;
    char* At_b = (char*)&At[0][0] + wv * 1024;
    char* Bt_b = (char*)&Bt[0][0] + wv * 1024;

    for (int k0 = 0; k0 < K; k0 += 32) {
        gload_lds16(pa0 + k0, At_b);
        gload_lds16(pa1 + k0, At_b + 4096);
        gload_lds16(pb0 + k0, Bt_b);
        gload_lds16(pb1 + k0, Bt_b + 4096);
        __syncthreads();

        bf8_t af[4], bfr[4];
        #pragma unroll
        for (int mi = 0; mi < 4; ++mi)
            af[mi] = *(const bf8_t*)((const char*)&At[0][0] +
                     (wr * 64 + mi * 16 + (lane & 15)) * 64 + (lane >> 4) * 16);
        #pragma unroll
        for (int ni = 0; ni < 4; ++ni)
            bfr[ni] = *(const bf8_t*)((const char*)&Bt[0][0] +
                     (wc * 64 + ni * 16 + (lane & 15)) * 64 + (lane >> 4) * 16);
        #pragma unroll
        for (int mi = 0; mi < 4; ++mi)
            #pragma unroll
            for (int ni = 0; ni < 4; ++ni)
                acc[mi][ni] = __builtin_amdgcn_mfma_f32_16x16x32_bf16(
                    af[mi], bfr[ni], acc[mi][ni], 0, 0, 0);
        __syncthreads();
    }

    #pragma unroll
    for (int mi = 0; mi < 4; ++mi) {
        int r0 = bm + wr * 64 + mi * 16 + (lane >> 4) * 4;
        #pragma unroll
        for (int ni = 0; ni < 4; ++ni) {
            int c0 = bn + wc * 64 + ni * 16 + (lane & 15);
            #pragma unroll
            for (int j = 0; j < 4; ++j)
                Cout[(size_t)(r0 + j) * N + c0] = acc[mi][ni][j];
        }
    }
}

// ---------------------------------------------------------------------------
// Low-rank stage 1 (f32)
// ---------------------------------------------------------------------------
__global__ __launch_bounds__(256) void lr1_kernel(
    const float* __restrict__ X, const float* __restrict__ mixv,
    const float* __restrict__ M1, float* __restrict__ Hout,
    int D, int act, int Tlen)
{
    __shared__ float row[Cdim];
    __shared__ float red[256];
    int m = blockIdx.x;
    int tid = threadIdx.x;
    int t = m % Tlen;
    const float* xr = X + (size_t)m * Cdim;
    #pragma unroll
    for (int q = 0; q < 4; ++q) {
        int kq = tid + q * 256;
        float v = xr[kq];
        float pv = (t > 0) ? xr[kq - Cdim] : 0.f;
        row[kq] = v + (pv - v) * mixv[kq];
    }
    __syncthreads();
    int P = 256 / D;
    int p = tid / D, n = tid % D;
    int klen = Cdim / P;
    float acc = 0.f;
    int kend = (p + 1) * klen;
    for (int k = p * klen; k < kend; ++k)
        acc += row[k] * M1[(size_t)k * D + n];
    red[tid] = acc;
    __syncthreads();
    if (tid < D) {
        float s = 0.f;
        for (int q = 0; q < P; ++q) s += red[tid + q * D];
        if (act == 1) s = sigf(s);
        else if (act == 2) s = tanhf(s);
        Hout[(size_t)m * D + tid] = s;
    }
}

// ---------------------------------------------------------------------------
// Low-rank stage 2. act: 0 none, 1 sigmoid, 3 sigmoid*e^-0.5.
// ---------------------------------------------------------------------------
__global__ __launch_bounds__(256) void lr2_kernel(
    const float* __restrict__ Hin, const float* __restrict__ M2,
    const float* __restrict__ bias, float* __restrict__ OutF,
    __hip_bfloat16* __restrict__ OutB, int D, int act)
{
    __shared__ float hs[128];
    int m = blockIdx.y;
    int n = blockIdx.x * 256 + threadIdx.x;
    if (threadIdx.x < D) hs[threadIdx.x] = Hin[(size_t)m * D + threadIdx.x];
    __syncthreads();
    float acc = bias ? bias[n] : 0.f;
    for (int k = 0; k < D; ++k)
        acc += hs[k] * M2[(size_t)k * Cdim + n];
    if (act == 1) acc = sigf(acc);
    else if (act == 3) acc = sigf(acc) * 0.60653065971263342f;
    size_t oi = (size_t)m * Cdim + n;
    if (OutB) OutB[oi] = __float2bfloat16(acc);
    else OutF[oi] = acc;
}

// ---------------------------------------------------------------------------
// E1: kk-normalize -> aarr=-kkn, barr=kkn*at; ut; v_first passthrough.
// ---------------------------------------------------------------------------
__global__ __launch_bounds__(256) void e1_kernel(
    const float* __restrict__ kt, const __hip_bfloat16* __restrict__ at16,
    const float* __restrict__ rt, const float* __restrict__ vraw,
    const float* __restrict__ vt, const float* __restrict__ vfirst,
    const float* __restrict__ k_k, const float* __restrict__ k_a,
    const float* __restrict__ r_k,
    float* __restrict__ aarr, float* __restrict__ barr,
    float* __restrict__ ut, float* __restrict__ out2)
{
    int gid = blockIdx.x * 4 + (threadIdx.x >> 6);
    int lane = threadIdx.x & 63;
    int h = gid % Hdim;
    size_t idx = (size_t)gid * 64 + lane;
    int c = h * 64 + lane;
    float ktv = kt[idx];
    float atv = __bfloat162float(at16[idx]);
    float kk = ktv * k_k[c];
    float ss = wsum64(kk * kk);
    float norm = sqrtf(ss);
    float kkn = kk / fmaxf(norm, 1e-12f);
    aarr[idx] = -kkn;
    barr[idx] = kkn * atv;
    float kmix = ktv * (1.f + (atv - 1.f) * k_a[c]);
    float rv = rt[idx];
    float dot = wsum64(rv * kmix * r_k[c]);
    float vm = vraw[idx];
    float vf = vfirst[idx];
    vm = vm + (vf - vm) * vt[idx];
    ut[idx] = dot * vm;
    out2[idx] = vf;
}

// ---------------------------------------------------------------------------
// WKV scan: barrier-free, asm-forced batched loads, double-buffered.
// Block = 512 thr = 2 (b,h) groups; 4 waves/group; wave owns 16 rows,
// 4 lanes/row (lane = i_loc*4+q owns cols [16q,16q+16)).
// Each step's 21 operand loads are ONE asm volatile block with "=&v"
// outputs -> allocator must keep all 81 results live (R4/R5 failure: the
// compiler serialized load->wait->use, 21 x ~250cyc L2 = 5200 cyc/step).
// Counted s_waitcnt vmcnt(21) (next set stays in flight) + sched_barrier.
// Quad reduces via DPP (VALU) instead of shfl (LDS pipe).
// ---------------------------------------------------------------------------
struct Ops { f4 a[4], d[4], k[4], b[4], r[4]; float vi; };

static __device__ __forceinline__ void load_set(
    Ops& s, const float* pa, const float* pd, const float* pk,
    const float* pb, const float* pr, const float* pv)
{
    asm volatile(
        "global_load_dwordx4 %0, %21, off\n\t"
        "global_load_dwordx4 %1, %21, off offset:16\n\t"
        "global_load_dwordx4 %2, %21, off offset:32\n\t"
        "global_load_dwordx4 %3, %21, off offset:48\n\t"
        "global_load_dword   %20, %26, off\n\t"
        "global_load_dwordx4 %4, %22, off\n\t"
        "global_load_dwordx4 %5, %22, off offset:16\n\t"
        "global_load_dwordx4 %6, %22, off offset:32\n\t"
        "global_load_dwordx4 %7, %22, off offset:48\n\t"
        "global_load_dwordx4 %8, %23, off\n\t"
        "global_load_dwordx4 %9, %23, off offset:16\n\t"
        "global_load_dwordx4 %10, %23, off offset:32\n\t"
        "global_load_dwordx4 %11, %23, off offset:48\n\t"
        "global_load_dwordx4 %12, %24, off\n\t"
        "global_load_dwordx4 %13, %24, off offset:16\n\t"
        "global_load_dwordx4 %14, %24, off offset:32\n\t"
        "global_load_dwordx4 %15, %24, off offset:48\n\t"
        "global_load_dwordx4 %16, %25, off\n\t"
        "global_load_dwordx4 %17, %25, off offset:16\n\t"
        "global_load_dwordx4 %18, %25, off offset:32\n\t"
        "global_load_dwordx4 %19, %25, off offset:48"
        : "=&v"(s.a[0]), "=&v"(s.a[1]), "=&v"(s.a[2]), "=&v"(s.a[3]),
          "=&v"(s.d[0]), "=&v"(s.d[1]), "=&v"(s.d[2]), "=&v"(s.d[3]),
          "=&v"(s.k[0]), "=&v"(s.k[1]), "=&v"(s.k[2]), "=&v"(s.k[3]),
          "=&v"(s.b[0]), "=&v"(s.b[1]), "=&v"(s.b[2]), "=&v"(s.b[3]),
          "=&v"(s.r[0]), "=&v"(s.r[1]), "=&v"(s.r[2]), "=&v"(s.r[3]),
          "=&v"(s.vi)
        : "v"(pa), "v"(pd), "v"(pk), "v"(pb), "v"(pr), "v"(pv));
}

static __device__ __forceinline__ void wkv_wait() {
    asm volatile("s_waitcnt vmcnt(21)" ::: "memory");
    __builtin_amdgcn_sched_barrier(0);
}

static __device__ __forceinline__ void wkv_compute(
    float S[16], const Ops& o, float* po, int q)
{
    float s0 = 0.f, s1 = 0.f, s2 = 0.f, s3 = 0.f;
    #pragma unroll
    for (int c = 0; c < 4; ++c) {
        s0 = fmaf(S[c*4+0], o.a[c].x, s0);
        s1 = fmaf(S[c*4+1], o.a[c].y, s1);
        s2 = fmaf(S[c*4+2], o.a[c].z, s2);
        s3 = fmaf(S[c*4+3], o.a[c].w, s3);
    }
    float sp = quad_reduce((s0 + s1) + (s2 + s3));
    float o0 = 0.f, o1 = 0.f, o2 = 0.f, o3 = 0.f;
    #pragma unroll
    for (int c = 0; c < 4; ++c) {
        S[c*4+0] = fmaf(S[c*4+0], o.d[c].x, fmaf(sp, o.b[c].x, o.vi * o.k[c].x));
        S[c*4+1] = fmaf(S[c*4+1], o.d[c].y, fmaf(sp, o.b[c].y, o.vi * o.k[c].y));
        S[c*4+2] = fmaf(S[c*4+2], o.d[c].z, fmaf(sp, o.b[c].z, o.vi * o.k[c].z));
        S[c*4+3] = fmaf(S[c*4+3], o.d[c].w, fmaf(sp, o.b[c].w, o.vi * o.k[c].w));
        o0 = fmaf(S[c*4+0], o.r[c].x, o0);
        o1 = fmaf(S[c*4+1], o.r[c].y, o1);
        o2 = fmaf(S[c*4+2], o.r[c].z, o2);
        o3 = fmaf(S[c*4+3], o.r[c].w, o3);
    }
    float op = quad_reduce((o0 + o1) + (o2 + o3));
    if (q == 0) *po = op;
}

__global__ __launch_bounds__(512, 2) void wkv_kernel(
    const float* __restrict__ rt, const float* __restrict__ decay,
    const float* __restrict__ kt, const float* __restrict__ vt,
    const float* __restrict__ aarr, const float* __restrict__ barr,
    float* __restrict__ wkvt)
{
    int tid = threadIdx.x;
    int wave = tid >> 6, lane = tid & 63;
    int g = wave >> 2, w = wave & 3;
    int bh = blockIdx.x * 2 + g;
    int b = bh >> 4, h = bh & 15;
    int i = w * 16 + (lane >> 2);
    int q = lane & 3;
    int jb = q * 16;
    size_t base = ((size_t)b * Tdim) * Cdim + (size_t)h * Ndim;
    const float* pa = aarr + base + jb;
    const float* pd = decay + base + jb;
    const float* pk = kt + base + jb;
    const float* pb = barr + base + jb;
    const float* pr = rt + base + jb;
    const float* pv = vt + base + i;
    float* po = wkvt + base + i;

    float S[16];
    #pragma unroll
    for (int j = 0; j < 16; ++j) S[j] = 0.f;

    Ops A, B;
    load_set(A, pa, pd, pk, pb, pr, pv);
    for (int t = 0; t < Tdim; t += 2) {
        size_t off1 = (size_t)(t + 1) * Cdim;
        load_set(B, pa + off1, pd + off1, pk + off1, pb + off1, pr + off1, pv + off1);
        wkv_wait();
        wkv_compute(S, A, po + (size_t)t * Cdim, q);
        size_t off2 = (size_t)((t + 2 < Tdim) ? t + 2 : Tdim - 1) * Cdim;
        load_set(A, pa + off2, pd + off2, pk + off2, pb + off2, pr + off2, pv + off2);
        wkv_wait();
        wkv_compute(S, B, po + off1, q);
    }
}

// ---------------------------------------------------------------------------
// E2: pt = GroupNorm(rt*wkvt)*ln_g + ln_b + ut; g16 = bf16(gt*pt)
// ---------------------------------------------------------------------------
__global__ __launch_bounds__(256) void e2_kernel(
    const float* __restrict__ rt, const float* __restrict__ wkvt,
    const float* __restrict__ ut, const __hip_bfloat16* __restrict__ gt16,
    const float* __restrict__ ln_g, const float* __restrict__ ln_b,
    __hip_bfloat16* __restrict__ g16)
{
    int gid = blockIdx.x * 4 + (threadIdx.x >> 6);
    int lane = threadIdx.x & 63;
    int h = gid % Hdim;
    size_t idx = (size_t)gid * 64 + lane;
    int c = h * 64 + lane;
    float x = rt[idx] * wkvt[idx];
    float mu = wsum64(x) * (1.f / 64.f);
    float d = x - mu;
    float var = wsum64(d * d) * (1.f / 64.f);
    float xn = d / sqrtf(var + EPS_GN);
    float pt = xn * ln_g[c] + ln_b[c] + ut[idx];
    float res = __bfloat162float(gt16[idx]) * pt;
    g16[idx] = __float2bfloat16(res);
}

// ---------------------------------------------------------------------------
extern "C" void kernel_launch(void* const* d_in, const int* in_sizes, int n_in,
                              void* d_out, int out_size, void* d_ws, size_t ws_size,
                              hipStream_t stream)
{
    (void)in_sizes; (void)n_in; (void)out_size; (void)ws_size;
    const float* xt      = (const float*)d_in[0];
    const float* v_first = (const float*)d_in[1];
    const float* tmix_r  = (const float*)d_in[2];
    const float* tmix_w  = (const float*)d_in[3];
    const float* tmix_k  = (const float*)d_in[4];
    const float* tmix_v  = (const float*)d_in[5];
    const float* tmix_a  = (const float*)d_in[6];
    const float* tmix_g  = (const float*)d_in[7];
    const float* w1 = (const float*)d_in[8];
    const float* w2 = (const float*)d_in[9];
    const float* w0 = (const float*)d_in[10];
    const float* a1 = (const float*)d_in[11];
    const float* a2 = (const float*)d_in[12];
    const float* a0 = (const float*)d_in[13];
    const float* v1 = (const float*)d_in[14];
    const float* v2 = (const float*)d_in[15];
    const float* v0 = (const float*)d_in[16];
    const float* g1 = (const float*)d_in[17];
    const float* g2 = (const float*)d_in[18];
    const float* k_k = (const float*)d_in[19];
    const float* k_a = (const float*)d_in[20];
    const float* r_k = (const float*)d_in[21];
    const float* W_r = (const float*)d_in[22];
    const float* W_k = (const float*)d_in[23];
    const float* W_v = (const float*)d_in[24];
    const float* W_o = (const float*)d_in[25];
    const float* ln_g = (const float*)d_in[26];
    const float* ln_b = (const float*)d_in[27];

    float* out = (float*)d_out;
    const size_t BTC = (size_t)Bdim * Tdim * Cdim;   // 2,097,152
    const int M = Bdim * Tdim;                        // 2048

    float* ws = (float*)d_ws;
    float* rt    = ws + 0 * BTC;
    float* kt    = ws + 1 * BTC;
    float* vraw  = ws + 2 * BTC;
    float* vt    = ws + 3 * BTC;
    float* decay = ws + 4 * BTC;
    float* aarr  = ws + 5 * BTC;
    float* barr  = ws + 6 * BTC;
    float* ut    = ws + 7 * BTC;
    float* wkv   = ws + 8 * BTC;
    __hip_bfloat16* bfa = (__hip_bfloat16*)(ws + 9 * BTC);
    __hip_bfloat16* at16 = bfa + 0 * BTC;
    __hip_bfloat16* gt16 = bfa + 1 * BTC;
    __hip_bfloat16* xr16 = bfa + 2 * BTC;
    __hip_bfloat16* xk16 = bfa + 3 * BTC;
    __hip_bfloat16* xv16 = bfa + 4 * BTC;   // reused as g16 after gemm_v
    __hip_bfloat16* Wb   = bfa + 5 * BTC;   // 4*CCdim = 2*BTC bf16
    float* hbuf = (float*)(bfa + 7 * BTC);
    __hip_bfloat16* g16 = xv16;

    // prep: weights + lerped activations -> bf16
    wconv_kernel<<<2048, 256, 0, stream>>>(W_r, W_k, W_v, W_o, Wb);
    prep_x<<<1024, 256, 0, stream>>>(xt, tmix_r, tmix_k, tmix_v, xr16, xk16, xv16);

    // big projections (bf16 MFMA)
    dim3 gg(Cdim / 128, M / 128);   // (8,16)
    gemm_mfma<<<gg, 256, 0, stream>>>(xr16, Wb + 0 * (size_t)CCdim, rt,   M, Cdim, Cdim);
    gemm_mfma<<<gg, 256, 0, stream>>>(xk16, Wb + 1 * (size_t)CCdim, kt,   M, Cdim, Cdim);
    gemm_mfma<<<gg, 256, 0, stream>>>(xv16, Wb + 2 * (size_t)CCdim, vraw, M, Cdim, Cdim);

    // low-rank paths
    lr1_kernel<<<M, 256, 0, stream>>>(xt, tmix_w, w1, hbuf, 64, 2, Tdim);
    lr2_kernel<<<dim3(Cdim / 256, M), 256, 0, stream>>>(hbuf, w2, w0, decay, nullptr, 64, 3);
    lr1_kernel<<<M, 256, 0, stream>>>(xt, tmix_a, a1, hbuf, 64, 0, Tdim);
    lr2_kernel<<<dim3(Cdim / 256, M), 256, 0, stream>>>(hbuf, a2, a0, nullptr, at16, 64, 1);
    lr1_kernel<<<M, 256, 0, stream>>>(xt, tmix_v, v1, hbuf, 32, 0, Tdim);
    lr2_kernel<<<dim3(Cdim / 256, M), 256, 0, stream>>>(hbuf, v2, v0, vt, nullptr, 32, 1);
    lr1_kernel<<<M, 256, 0, stream>>>(xt, tmix_g, g1, hbuf, 128, 1, Tdim);
    lr2_kernel<<<dim3(Cdim / 256, M), 256, 0, stream>>>(hbuf, g2, nullptr, nullptr, gt16, 128, 0);

    // E1
    e1_kernel<<<(Bdim * Tdim * Hdim) / 4, 256, 0, stream>>>(
        kt, at16, rt, vraw, vt, v_first, k_k, k_a, r_k,
        aarr, barr, ut, out + BTC);

    // WKV scan (asm-batched loads, double-buffered)
    wkv_kernel<<<(Bdim * Hdim) / 2, 512, 0, stream>>>(rt, decay, kt, vt, aarr, barr, wkv);

    // E2 (writes bf16 gated output)
    e2_kernel<<<(Bdim * Tdim * Hdim) / 4, 256, 0, stream>>>(
        rt, wkv, ut, gt16, ln_g, ln_b, g16);

    // output projection (bf16 MFMA)
    gemm_mfma<<<gg, 256, 0, stream>>>(g16, Wb + 3 * (size_t)CCdim, out, M, Cdim, Cdim);
}

// Round 7
// 1108.081 us; speedup vs baseline: 2.4837x; 2.4820x over previous
//
#include <hip/hip_runtime.h>
#include <hip/hip_bf16.h>
#include <math.h>

#define Bdim 2
#define Tdim 1024
#define Cdim 1024
#define Hdim 16
#define Ndim 64
#define CCdim (Cdim * Cdim)
#define EPS_GN 0.00064f

typedef __bf16 bf8_t __attribute__((ext_vector_type(8)));
typedef float f32x4 __attribute__((ext_vector_type(4)));
typedef float f4 __attribute__((ext_vector_type(4)));

static __device__ __forceinline__ float sigf(float x) { return 1.f / (1.f + expf(-x)); }

static __device__ __forceinline__ float wsum64(float v) {
    #pragma unroll
    for (int m = 1; m < 64; m <<= 1) v += __shfl_xor(v, m);
    return v;
}

static __device__ __forceinline__ void gload_lds16(const void* g, void* l) {
    __builtin_amdgcn_global_load_lds(
        (const __attribute__((address_space(1))) void*)g,
        (__attribute__((address_space(3))) void*)l, 16, 0, 0);
}

// quad (4-lane) reduce via DPP quad_perm: xor1 then xor2, VALU-speed.
static __device__ __forceinline__ float quad_reduce(float x) {
    int s1 = __builtin_amdgcn_update_dpp(0, __builtin_bit_cast(int, x),
                                         0xB1, 0xF, 0xF, true);   // [1,0,3,2]
    float y = x + __builtin_bit_cast(float, s1);
    int s2 = __builtin_amdgcn_update_dpp(0, __builtin_bit_cast(int, y),
                                         0x4E, 0xF, 0xF, true);   // [2,3,0,1]
    return y + __builtin_bit_cast(float, s2);
}

// ---------------------------------------------------------------------------
// Convert 4 weight matrices (C x C, row-major [n][k]) to bf16.
// ---------------------------------------------------------------------------
__global__ __launch_bounds__(256) void wconv_kernel(
    const float* __restrict__ W0, const float* __restrict__ W1,
    const float* __restrict__ W2, const float* __restrict__ W3,
    __hip_bfloat16* __restrict__ Wb)
{
    int blk = blockIdx.x;                 // 2048 blocks, 512 per matrix
    int which = blk >> 9;
    const float* src = (which == 0) ? W0 : (which == 1) ? W1 : (which == 2) ? W2 : W3;
    size_t e8 = ((size_t)(blk & 511) * 256 + threadIdx.x) * 8;
    float c[8];
    *(float4*)&c[0] = ((const float4*)(src + e8))[0];
    *(float4*)&c[4] = ((const float4*)(src + e8))[1];
    __hip_bfloat16 o[8];
    #pragma unroll
    for (int j = 0; j < 8; ++j) o[j] = __float2bfloat16(c[j]);
    __hip_bfloat16* dst = Wb + (size_t)which * CCdim + e8;
    ((ushort4*)dst)[0] = *(ushort4*)&o[0];
    ((ushort4*)dst)[1] = *(ushort4*)&o[4];
}

// ---------------------------------------------------------------------------
// Token-shift lerp for 3 mixes + bf16 convert: xr16, xk16, xv16.
// ---------------------------------------------------------------------------
__global__ __launch_bounds__(256) void prep_x(
    const float* __restrict__ xt,
    const float* __restrict__ mr, const float* __restrict__ mk, const float* __restrict__ mv,
    __hip_bfloat16* __restrict__ xr16, __hip_bfloat16* __restrict__ xk16,
    __hip_bfloat16* __restrict__ xv16)
{
    int idx8 = blockIdx.x * 256 + threadIdx.x;   // 0..262143
    int m = idx8 >> 7;
    int c8 = (idx8 & 127) * 8;
    int t = m & (Tdim - 1);
    const float* p = xt + (size_t)idx8 * 8;
    float cur[8], prv[8];
    *(float4*)&cur[0] = ((const float4*)p)[0];
    *(float4*)&cur[4] = ((const float4*)p)[1];
    if (t > 0) {
        *(float4*)&prv[0] = ((const float4*)(p - Cdim))[0];
        *(float4*)&prv[4] = ((const float4*)(p - Cdim))[1];
    } else {
        #pragma unroll
        for (int j = 0; j < 8; ++j) prv[j] = 0.f;
    }
    float mx[8];
    __hip_bfloat16 o[8];
    size_t ob = (size_t)idx8 * 8;

    *(float4*)&mx[0] = *(const float4*)(mr + c8);
    *(float4*)&mx[4] = *(const float4*)(mr + c8 + 4);
    #pragma unroll
    for (int j = 0; j < 8; ++j) o[j] = __float2bfloat16(cur[j] + (prv[j] - cur[j]) * mx[j]);
    ((ushort4*)(xr16 + ob))[0] = *(ushort4*)&o[0];
    ((ushort4*)(xr16 + ob))[1] = *(ushort4*)&o[4];

    *(float4*)&mx[0] = *(const float4*)(mk + c8);
    *(float4*)&mx[4] = *(const float4*)(mk + c8 + 4);
    #pragma unroll
    for (int j = 0; j < 8; ++j) o[j] = __float2bfloat16(cur[j] + (prv[j] - cur[j]) * mx[j]);
    ((ushort4*)(xk16 + ob))[0] = *(ushort4*)&o[0];
    ((ushort4*)(xk16 + ob))[1] = *(ushort4*)&o[4];

    *(float4*)&mx[0] = *(const float4*)(mv + c8);
    *(float4*)&mx[4] = *(const float4*)(mv + c8 + 4);
    #pragma unroll
    for (int j = 0; j < 8; ++j) o[j] = __float2bfloat16(cur[j] + (prv[j] - cur[j]) * mx[j]);
    ((ushort4*)(xv16 + ob))[0] = *(ushort4*)&o[0];
    ((ushort4*)(xv16 + ob))[1] = *(ushort4*)&o[4];
}

// ---------------------------------------------------------------------------
// bf16 MFMA GEMM: Cout[m][n] = sum_k A[m][k] * Bw[n][k], f32 out.
// ---------------------------------------------------------------------------
__global__ __launch_bounds__(256) void gemm_mfma(
    const __hip_bfloat16* __restrict__ A, const __hip_bfloat16* __restrict__ Bw,
    float* __restrict__ Cout, int M, int N, int K)
{
    __shared__ unsigned short At[128][32];
    __shared__ unsigned short Bt[128][32];
    int tid = threadIdx.x;
    int lane = tid & 63, wv = tid >> 6;
    int bm = blockIdx.y * 128, bn = blockIdx.x * 128;
    int wr = wv >> 1, wc = wv & 1;

    f32x4 acc[4][4];
    #pragma unroll
    for (int mi = 0; mi < 4; ++mi)
        #pragma unroll
        for (int ni = 0; ni < 4; ++ni)
            acc[mi][ni] = (f32x4){0.f, 0.f, 0.f, 0.f};

    int srow = wv * 16 + (lane >> 2);
    int scol = (lane & 3) * 8;
    const __hip_bfloat16* pa0 = A + (size_t)(bm + srow) * K + scol;
    const __hip_bfloat16* pa1 = A + (size_t)(bm + 64 + srow) * K + scol;
    const __hip_bfloat16* pb0 = Bw + (size_t)(bn + srow) * K + scol;
    const __hip_bfloat16* pb1 = Bw + (size_t)(bn + 64 + srow) * K + scol;
    char* At_b = (char*)&At[0][0] + wv * 1024;
    char* Bt_b = (char*)&Bt[0][0] + wv * 1024;

    for (int k0 = 0; k0 < K; k0 += 32) {
        gload_lds16(pa0 + k0, At_b);
        gload_lds16(pa1 + k0, At_b + 4096);
        gload_lds16(pb0 + k0, Bt_b);
        gload_lds16(pb1 + k0, Bt_b + 4096);
        __syncthreads();

        bf8_t af[4], bfr[4];
        #pragma unroll
        for (int mi = 0; mi < 4; ++mi)
            af[mi] = *(const bf8_t*)((const char*)&At[0][0] +
                     (wr * 64 + mi * 16 + (lane & 15)) * 64 + (lane >> 4) * 16);
        #pragma unroll
        for (int ni = 0; ni < 4; ++ni)
            bfr[ni] = *(const bf8_t*)((const char*)&Bt[0][0] +
                     (wc * 64 + ni * 16 + (lane & 15)) * 64 + (lane >> 4) * 16);
        #pragma unroll
        for (int mi = 0; mi < 4; ++mi)
            #pragma unroll
            for (int ni = 0; ni < 4; ++ni)
                acc[mi][ni] = __builtin_amdgcn_mfma_f32_16x16x32_bf16(
                    af[mi], bfr[ni], acc[mi][ni], 0, 0, 0);
        __syncthreads();
    }

    #pragma unroll
    for (int mi = 0; mi < 4; ++mi) {
        int r0 = bm + wr * 64 + mi * 16 + (lane >> 4) * 4;
        #pragma unroll
        for (int ni = 0; ni < 4; ++ni) {
            int c0 = bn + wc * 64 + ni * 16 + (lane & 15);
            #pragma unroll
            for (int j = 0; j < 4; ++j)
                Cout[(size_t)(r0 + j) * N + c0] = acc[mi][ni][j];
        }
    }
}

// ---------------------------------------------------------------------------
// Low-rank stage 1 (f32)
// ---------------------------------------------------------------------------
__global__ __launch_bounds__(256) void lr1_kernel(
    const float* __restrict__ X, const float* __restrict__ mixv,
    const float* __restrict__ M1, float* __restrict__ Hout,
    int D, int act, int Tlen)
{
    __shared__ float row[Cdim];
    __shared__ float red[256];
    int m = blockIdx.x;
    int tid = threadIdx.x;
    int t = m % Tlen;
    const float* xr = X + (size_t)m * Cdim;
    #pragma unroll
    for (int q = 0; q < 4; ++q) {
        int kq = tid + q * 256;
        float v = xr[kq];
        float pv = (t > 0) ? xr[kq - Cdim] : 0.f;
        row[kq] = v + (pv - v) * mixv[kq];
    }
    __syncthreads();
    int P = 256 / D;
    int p = tid / D, n = tid % D;
    int klen = Cdim / P;
    float acc = 0.f;
    int kend = (p + 1) * klen;
    for (int k = p * klen; k < kend; ++k)
        acc += row[k] * M1[(size_t)k * D + n];
    red[tid] = acc;
    __syncthreads();
    if (tid < D) {
        float s = 0.f;
        for (int q = 0; q < P; ++q) s += red[tid + q * D];
        if (act == 1) s = sigf(s);
        else if (act == 2) s = tanhf(s);
        Hout[(size_t)m * D + tid] = s;
    }
}

// ---------------------------------------------------------------------------
// Low-rank stage 2. act: 0 none, 1 sigmoid, 3 sigmoid*e^-0.5.
// ---------------------------------------------------------------------------
__global__ __launch_bounds__(256) void lr2_kernel(
    const float* __restrict__ Hin, const float* __restrict__ M2,
    const float* __restrict__ bias, float* __restrict__ OutF,
    __hip_bfloat16* __restrict__ OutB, int D, int act)
{
    __shared__ float hs[128];
    int m = blockIdx.y;
    int n = blockIdx.x * 256 + threadIdx.x;
    if (threadIdx.x < D) hs[threadIdx.x] = Hin[(size_t)m * D + threadIdx.x];
    __syncthreads();
    float acc = bias ? bias[n] : 0.f;
    for (int k = 0; k < D; ++k)
        acc += hs[k] * M2[(size_t)k * Cdim + n];
    if (act == 1) acc = sigf(acc);
    else if (act == 3) acc = sigf(acc) * 0.60653065971263342f;
    size_t oi = (size_t)m * Cdim + n;
    if (OutB) OutB[oi] = __float2bfloat16(acc);
    else OutF[oi] = acc;
}

// ---------------------------------------------------------------------------
// E1: kk-normalize -> aarr=-kkn, barr=kkn*at; ut; v_first passthrough.
// ---------------------------------------------------------------------------
__global__ __launch_bounds__(256) void e1_kernel(
    const float* __restrict__ kt, const __hip_bfloat16* __restrict__ at16,
    const float* __restrict__ rt, const float* __restrict__ vraw,
    const float* __restrict__ vt, const float* __restrict__ vfirst,
    const float* __restrict__ k_k, const float* __restrict__ k_a,
    const float* __restrict__ r_k,
    float* __restrict__ aarr, float* __restrict__ barr,
    float* __restrict__ ut, float* __restrict__ out2)
{
    int gid = blockIdx.x * 4 + (threadIdx.x >> 6);
    int lane = threadIdx.x & 63;
    int h = gid % Hdim;
    size_t idx = (size_t)gid * 64 + lane;
    int c = h * 64 + lane;
    float ktv = kt[idx];
    float atv = __bfloat162float(at16[idx]);
    float kk = ktv * k_k[c];
    float ss = wsum64(kk * kk);
    float norm = sqrtf(ss);
    float kkn = kk / fmaxf(norm, 1e-12f);
    aarr[idx] = -kkn;
    barr[idx] = kkn * atv;
    float kmix = ktv * (1.f + (atv - 1.f) * k_a[c]);
    float rv = rt[idx];
    float dot = wsum64(rv * kmix * r_k[c]);
    float vm = vraw[idx];
    float vf = vfirst[idx];
    vm = vm + (vf - vm) * vt[idx];
    ut[idx] = dot * vm;
    out2[idx] = vf;
}

// ---------------------------------------------------------------------------
// WKV scan v3: barrier-free, 8 lanes/row, asm-batched loads, 2-deep reg
// double buffer. One (b,h) per 512-thread block (grid 32). Lane tid:
// row i = tid>>3, cols [ (tid&7)*8, +8 ). Per operand set: 10 dwordx4 +
// 1 dword = 41 VGPR -> 2 sets + S[8] + addrs ~ 110 VGPR (fits; R6 failed
// because 2x81-reg sets forced spill-after-load => full serialization).
// Counted s_waitcnt vmcnt(11): the 11 newest ops (next set's loads) stay
// in flight; older set + store retire (in-order vmcnt).
// ---------------------------------------------------------------------------
struct Ops { f4 a0, a1, d0, d1, k0, k1, b0, b1, r0, r1; float vi; };

static __device__ __forceinline__ void load_set(
    Ops& s, const float* pa, const float* pd, const float* pk,
    const float* pb, const float* pr, const float* pv)
{
    asm volatile(
        "global_load_dwordx4 %0, %11, off\n\t"
        "global_load_dwordx4 %1, %11, off offset:16\n\t"
        "global_load_dword   %10, %16, off\n\t"
        "global_load_dwordx4 %2, %12, off\n\t"
        "global_load_dwordx4 %3, %12, off offset:16\n\t"
        "global_load_dwordx4 %4, %13, off\n\t"
        "global_load_dwordx4 %5, %13, off offset:16\n\t"
        "global_load_dwordx4 %6, %14, off\n\t"
        "global_load_dwordx4 %7, %14, off offset:16\n\t"
        "global_load_dwordx4 %8, %15, off\n\t"
        "global_load_dwordx4 %9, %15, off offset:16"
        : "=&v"(s.a0), "=&v"(s.a1), "=&v"(s.d0), "=&v"(s.d1),
          "=&v"(s.k0), "=&v"(s.k1), "=&v"(s.b0), "=&v"(s.b1),
          "=&v"(s.r0), "=&v"(s.r1), "=&v"(s.vi)
        : "v"(pa), "v"(pd), "v"(pk), "v"(pb), "v"(pr), "v"(pv));
}

static __device__ __forceinline__ void wkv_wait() {
    asm volatile("s_waitcnt vmcnt(11)" ::: "memory");
    __builtin_amdgcn_sched_barrier(0);
}

static __device__ __forceinline__ void wkv_compute(
    float S[8], const Ops& o, float* po, int q)
{
    float s0 = 0.f, s1 = 0.f, s2 = 0.f, s3 = 0.f;
    s0 = fmaf(S[0], o.a0.x, s0); s1 = fmaf(S[1], o.a0.y, s1);
    s2 = fmaf(S[2], o.a0.z, s2); s3 = fmaf(S[3], o.a0.w, s3);
    s0 = fmaf(S[4], o.a1.x, s0); s1 = fmaf(S[5], o.a1.y, s1);
    s2 = fmaf(S[6], o.a1.z, s2); s3 = fmaf(S[7], o.a1.w, s3);
    float sp = quad_reduce((s0 + s1) + (s2 + s3));
    sp += __shfl_xor(sp, 4);

    S[0] = fmaf(S[0], o.d0.x, fmaf(sp, o.b0.x, o.vi * o.k0.x));
    S[1] = fmaf(S[1], o.d0.y, fmaf(sp, o.b0.y, o.vi * o.k0.y));
    S[2] = fmaf(S[2], o.d0.z, fmaf(sp, o.b0.z, o.vi * o.k0.z));
    S[3] = fmaf(S[3], o.d0.w, fmaf(sp, o.b0.w, o.vi * o.k0.w));
    S[4] = fmaf(S[4], o.d1.x, fmaf(sp, o.b1.x, o.vi * o.k1.x));
    S[5] = fmaf(S[5], o.d1.y, fmaf(sp, o.b1.y, o.vi * o.k1.y));
    S[6] = fmaf(S[6], o.d1.z, fmaf(sp, o.b1.z, o.vi * o.k1.z));
    S[7] = fmaf(S[7], o.d1.w, fmaf(sp, o.b1.w, o.vi * o.k1.w));

    float o0 = S[0] * o.r0.x, o1 = S[1] * o.r0.y;
    float o2 = S[2] * o.r0.z, o3 = S[3] * o.r0.w;
    o0 = fmaf(S[4], o.r1.x, o0); o1 = fmaf(S[5], o.r1.y, o1);
    o2 = fmaf(S[6], o.r1.z, o2); o3 = fmaf(S[7], o.r1.w, o3);
    float op = quad_reduce((o0 + o1) + (o2 + o3));
    op += __shfl_xor(op, 4);
    if (q == 0) *po = op;
}

__global__ __launch_bounds__(512, 1) void wkv_kernel(
    const float* __restrict__ rt, const float* __restrict__ decay,
    const float* __restrict__ kt, const float* __restrict__ vt,
    const float* __restrict__ aarr, const float* __restrict__ barr,
    float* __restrict__ wkvt)
{
    int tid = threadIdx.x;
    int bh = blockIdx.x;
    int b = bh >> 4, h = bh & 15;
    int i = tid >> 3;            // state row 0..63
    int q = tid & 7;             // column-slice owner
    int jb = q * 8;
    size_t base = ((size_t)b * Tdim) * Cdim + (size_t)h * Ndim;
    const float* pa = aarr + base + jb;
    const float* pd = decay + base + jb;
    const float* pk = kt + base + jb;
    const float* pb = barr + base + jb;
    const float* pr = rt + base + jb;
    const float* pv = vt + base + i;
    float* po = wkvt + base + i;

    float S[8];
    #pragma unroll
    for (int j = 0; j < 8; ++j) S[j] = 0.f;

    Ops A, B;
    load_set(A, pa, pd, pk, pb, pr, pv);
    for (int t = 0; t < Tdim; t += 2) {
        size_t off1 = (size_t)(t + 1) * Cdim;
        load_set(B, pa + off1, pd + off1, pk + off1, pb + off1, pr + off1, pv + off1);
        wkv_wait();
        wkv_compute(S, A, po + (size_t)t * Cdim, q);
        size_t off2 = (size_t)((t + 2 < Tdim) ? t + 2 : Tdim - 1) * Cdim;
        load_set(A, pa + off2, pd + off2, pk + off2, pb + off2, pr + off2, pv + off2);
        wkv_wait();
        wkv_compute(S, B, po + off1, q);
    }
}

// ---------------------------------------------------------------------------
// E2: pt = GroupNorm(rt*wkvt)*ln_g + ln_b + ut; g16 = bf16(gt*pt)
// ---------------------------------------------------------------------------
__global__ __launch_bounds__(256) void e2_kernel(
    const float* __restrict__ rt, const float* __restrict__ wkvt,
    const float* __restrict__ ut, const __hip_bfloat16* __restrict__ gt16,
    const float* __restrict__ ln_g, const float* __restrict__ ln_b,
    __hip_bfloat16* __restrict__ g16)
{
    int gid = blockIdx.x * 4 + (threadIdx.x >> 6);
    int lane = threadIdx.x & 63;
    int h = gid % Hdim;
    size_t idx = (size_t)gid * 64 + lane;
    int c = h * 64 + lane;
    float x = rt[idx] * wkvt[idx];
    float mu = wsum64(x) * (1.f / 64.f);
    float d = x - mu;
    float var = wsum64(d * d) * (1.f / 64.f);
    float xn = d / sqrtf(var + EPS_GN);
    float pt = xn * ln_g[c] + ln_b[c] + ut[idx];
    float res = __bfloat162float(gt16[idx]) * pt;
    g16[idx] = __float2bfloat16(res);
}

// ---------------------------------------------------------------------------
extern "C" void kernel_launch(void* const* d_in, const int* in_sizes, int n_in,
                              void* d_out, int out_size, void* d_ws, size_t ws_size,
                              hipStream_t stream)
{
    (void)in_sizes; (void)n_in; (void)out_size; (void)ws_size;
    const float* xt      = (const float*)d_in[0];
    const float* v_first = (const float*)d_in[1];
    const float* tmix_r  = (const float*)d_in[2];
    const float* tmix_w  = (const float*)d_in[3];
    const float* tmix_k  = (const float*)d_in[4];
    const float* tmix_v  = (const float*)d_in[5];
    const float* tmix_a  = (const float*)d_in[6];
    const float* tmix_g  = (const float*)d_in[7];
    const float* w1 = (const float*)d_in[8];
    const float* w2 = (const float*)d_in[9];
    const float* w0 = (const float*)d_in[10];
    const float* a1 = (const float*)d_in[11];
    const float* a2 = (const float*)d_in[12];
    const float* a0 = (const float*)d_in[13];
    const float* v1 = (const float*)d_in[14];
    const float* v2 = (const float*)d_in[15];
    const float* v0 = (const float*)d_in[16];
    const float* g1 = (const float*)d_in[17];
    const float* g2 = (const float*)d_in[18];
    const float* k_k = (const float*)d_in[19];
    const float* k_a = (const float*)d_in[20];
    const float* r_k = (const float*)d_in[21];
    const float* W_r = (const float*)d_in[22];
    const float* W_k = (const float*)d_in[23];
    const float* W_v = (const float*)d_in[24];
    const float* W_o = (const float*)d_in[25];
    const float* ln_g = (const float*)d_in[26];
    const float* ln_b = (const float*)d_in[27];

    float* out = (float*)d_out;
    const size_t BTC = (size_t)Bdim * Tdim * Cdim;   // 2,097,152
    const int M = Bdim * Tdim;                        // 2048

    float* ws = (float*)d_ws;
    float* rt    = ws + 0 * BTC;
    float* kt    = ws + 1 * BTC;
    float* vraw  = ws + 2 * BTC;
    float* vt    = ws + 3 * BTC;
    float* decay = ws + 4 * BTC;
    float* aarr  = ws + 5 * BTC;
    float* barr  = ws + 6 * BTC;
    float* ut    = ws + 7 * BTC;
    float* wkv   = ws + 8 * BTC;
    __hip_bfloat16* bfa = (__hip_bfloat16*)(ws + 9 * BTC);
    __hip_bfloat16* at16 = bfa + 0 * BTC;
    __hip_bfloat16* gt16 = bfa + 1 * BTC;
    __hip_bfloat16* xr16 = bfa + 2 * BTC;
    __hip_bfloat16* xk16 = bfa + 3 * BTC;
    __hip_bfloat16* xv16 = bfa + 4 * BTC;   // reused as g16 after gemm_v
    __hip_bfloat16* Wb   = bfa + 5 * BTC;   // 4*CCdim = 2*BTC bf16
    float* hbuf = (float*)(bfa + 7 * BTC);
    __hip_bfloat16* g16 = xv16;

    // prep: weights + lerped activations -> bf16
    wconv_kernel<<<2048, 256, 0, stream>>>(W_r, W_k, W_v, W_o, Wb);
    prep_x<<<1024, 256, 0, stream>>>(xt, tmix_r, tmix_k, tmix_v, xr16, xk16, xv16);

    // big projections (bf16 MFMA)
    dim3 gg(Cdim / 128, M / 128);   // (8,16)
    gemm_mfma<<<gg, 256, 0, stream>>>(xr16, Wb + 0 * (size_t)CCdim, rt,   M, Cdim, Cdim);
    gemm_mfma<<<gg, 256, 0, stream>>>(xk16, Wb + 1 * (size_t)CCdim, kt,   M, Cdim, Cdim);
    gemm_mfma<<<gg, 256, 0, stream>>>(xv16, Wb + 2 * (size_t)CCdim, vraw, M, Cdim, Cdim);

    // low-rank paths
    lr1_kernel<<<M, 256, 0, stream>>>(xt, tmix_w, w1, hbuf, 64, 2, Tdim);
    lr2_kernel<<<dim3(Cdim / 256, M), 256, 0, stream>>>(hbuf, w2, w0, decay, nullptr, 64, 3);
    lr1_kernel<<<M, 256, 0, stream>>>(xt, tmix_a, a1, hbuf, 64, 0, Tdim);
    lr2_kernel<<<dim3(Cdim / 256, M), 256, 0, stream>>>(hbuf, a2, a0, nullptr, at16, 64, 1);
    lr1_kernel<<<M, 256, 0, stream>>>(xt, tmix_v, v1, hbuf, 32, 0, Tdim);
    lr2_kernel<<<dim3(Cdim / 256, M), 256, 0, stream>>>(hbuf, v2, v0, vt, nullptr, 32, 1);
    lr1_kernel<<<M, 256, 0, stream>>>(xt, tmix_g, g1, hbuf, 128, 1, Tdim);
    lr2_kernel<<<dim3(Cdim / 256, M), 256, 0, stream>>>(hbuf, g2, nullptr, nullptr, gt16, 128, 0);

    // E1
    e1_kernel<<<(Bdim * Tdim * Hdim) / 4, 256, 0, stream>>>(
        kt, at16, rt, vraw, vt, v_first, k_k, k_a, r_k,
        aarr, barr, ut, out + BTC);

    // WKV scan (8 lanes/row, asm-batched, 2-deep reg pipeline)
    wkv_kernel<<<Bdim * Hdim, 512, 0, stream>>>(rt, decay, kt, vt, aarr, barr, wkv);

    // E2 (writes bf16 gated output)
    e2_kernel<<<(Bdim * Tdim * Hdim) / 4, 256, 0, stream>>>(
        rt, wkv, ut, gt16, ln_g, ln_b, g16);

    // output projection (bf16 MFMA)
    gemm_mfma<<<gg, 256, 0, stream>>>(g16, Wb + 3 * (size_t)CCdim, out, M, Cdim, Cdim);
}

// Round 8
// 773.132 us; speedup vs baseline: 3.5597x; 1.4332x over previous
//
#include <hip/hip_runtime.h>
#include <hip/hip_bf16.h>
#include <math.h>

#define Bdim 2
#define Tdim 1024
#define Cdim 1024
#define Hdim 16
#define Ndim 64
#define CCdim (Cdim * Cdim)
#define EPS_GN 0.00064f

typedef __bf16 bf8_t __attribute__((ext_vector_type(8)));
typedef float f32x4 __attribute__((ext_vector_type(4)));
typedef float f4 __attribute__((ext_vector_type(4)));

static __device__ __forceinline__ float sigf(float x) { return 1.f / (1.f + expf(-x)); }

static __device__ __forceinline__ float wsum64(float v) {
    #pragma unroll
    for (int m = 1; m < 64; m <<= 1) v += __shfl_xor(v, m);
    return v;
}

static __device__ __forceinline__ void gload_lds16(const void* g, void* l) {
    __builtin_amdgcn_global_load_lds(
        (const __attribute__((address_space(1))) void*)g,
        (__attribute__((address_space(3))) void*)l, 16, 0, 0);
}

// quad (4-lane) reduce via DPP quad_perm: xor1 then xor2, VALU-speed.
static __device__ __forceinline__ float quad_reduce(float x) {
    int s1 = __builtin_amdgcn_update_dpp(0, __builtin_bit_cast(int, x),
                                         0xB1, 0xF, 0xF, true);   // [1,0,3,2]
    float y = x + __builtin_bit_cast(float, s1);
    int s2 = __builtin_amdgcn_update_dpp(0, __builtin_bit_cast(int, y),
                                         0x4E, 0xF, 0xF, true);   // [2,3,0,1]
    return y + __builtin_bit_cast(float, s2);
}

// ---------------------------------------------------------------------------
// Convert 4 weight matrices (C x C, row-major [n][k]) to bf16.
// ---------------------------------------------------------------------------
__global__ __launch_bounds__(256) void wconv_kernel(
    const float* __restrict__ W0, const float* __restrict__ W1,
    const float* __restrict__ W2, const float* __restrict__ W3,
    __hip_bfloat16* __restrict__ Wb)
{
    int blk = blockIdx.x;                 // 2048 blocks, 512 per matrix
    int which = blk >> 9;
    const float* src = (which == 0) ? W0 : (which == 1) ? W1 : (which == 2) ? W2 : W3;
    size_t e8 = ((size_t)(blk & 511) * 256 + threadIdx.x) * 8;
    float c[8];
    *(float4*)&c[0] = ((const float4*)(src + e8))[0];
    *(float4*)&c[4] = ((const float4*)(src + e8))[1];
    __hip_bfloat16 o[8];
    #pragma unroll
    for (int j = 0; j < 8; ++j) o[j] = __float2bfloat16(c[j]);
    __hip_bfloat16* dst = Wb + (size_t)which * CCdim + e8;
    ((ushort4*)dst)[0] = *(ushort4*)&o[0];
    ((ushort4*)dst)[1] = *(ushort4*)&o[4];
}

// ---------------------------------------------------------------------------
// Token-shift lerp for 3 mixes + bf16 convert: xr16, xk16, xv16.
// ---------------------------------------------------------------------------
__global__ __launch_bounds__(256) void prep_x(
    const float* __restrict__ xt,
    const float* __restrict__ mr, const float* __restrict__ mk, const float* __restrict__ mv,
    __hip_bfloat16* __restrict__ xr16, __hip_bfloat16* __restrict__ xk16,
    __hip_bfloat16* __restrict__ xv16)
{
    int idx8 = blockIdx.x * 256 + threadIdx.x;   // 0..262143
    int m = idx8 >> 7;
    int c8 = (idx8 & 127) * 8;
    int t = m & (Tdim - 1);
    const float* p = xt + (size_t)idx8 * 8;
    float cur[8], prv[8];
    *(float4*)&cur[0] = ((const float4*)p)[0];
    *(float4*)&cur[4] = ((const float4*)p)[1];
    if (t > 0) {
        *(float4*)&prv[0] = ((const float4*)(p - Cdim))[0];
        *(float4*)&prv[4] = ((const float4*)(p - Cdim))[1];
    } else {
        #pragma unroll
        for (int j = 0; j < 8; ++j) prv[j] = 0.f;
    }
    float mx[8];
    __hip_bfloat16 o[8];
    size_t ob = (size_t)idx8 * 8;

    *(float4*)&mx[0] = *(const float4*)(mr + c8);
    *(float4*)&mx[4] = *(const float4*)(mr + c8 + 4);
    #pragma unroll
    for (int j = 0; j < 8; ++j) o[j] = __float2bfloat16(cur[j] + (prv[j] - cur[j]) * mx[j]);
    ((ushort4*)(xr16 + ob))[0] = *(ushort4*)&o[0];
    ((ushort4*)(xr16 + ob))[1] = *(ushort4*)&o[4];

    *(float4*)&mx[0] = *(const float4*)(mk + c8);
    *(float4*)&mx[4] = *(const float4*)(mk + c8 + 4);
    #pragma unroll
    for (int j = 0; j < 8; ++j) o[j] = __float2bfloat16(cur[j] + (prv[j] - cur[j]) * mx[j]);
    ((ushort4*)(xk16 + ob))[0] = *(ushort4*)&o[0];
    ((ushort4*)(xk16 + ob))[1] = *(ushort4*)&o[4];

    *(float4*)&mx[0] = *(const float4*)(mv + c8);
    *(float4*)&mx[4] = *(const float4*)(mv + c8 + 4);
    #pragma unroll
    for (int j = 0; j < 8; ++j) o[j] = __float2bfloat16(cur[j] + (prv[j] - cur[j]) * mx[j]);
    ((ushort4*)(xv16 + ob))[0] = *(ushort4*)&o[0];
    ((ushort4*)(xv16 + ob))[1] = *(ushort4*)&o[4];
}

// ---------------------------------------------------------------------------
// bf16 MFMA GEMM: Cout[m][n] = sum_k A[m][k] * Bw[n][k], f32 out.
// ---------------------------------------------------------------------------
__global__ __launch_bounds__(256) void gemm_mfma(
    const __hip_bfloat16* __restrict__ A, const __hip_bfloat16* __restrict__ Bw,
    float* __restrict__ Cout, int M, int N, int K)
{
    __shared__ unsigned short At[128][32];
    __shared__ unsigned short Bt[128][32];
    int tid = threadIdx.x;
    int lane = tid & 63, wv = tid >> 6;
    int bm = blockIdx.y * 128, bn = blockIdx.x * 128;
    int wr = wv >> 1, wc = wv & 1;

    f32x4 acc[4][4];
    #pragma unroll
    for (int mi = 0; mi < 4; ++mi)
        #pragma unroll
        for (int ni = 0; ni < 4; ++ni)
            acc[mi][ni] = (f32x4){0.f, 0.f, 0.f, 0.f};

    int srow = wv * 16 + (lane >> 2);
    int scol = (lane & 3) * 8;
    const __hip_bfloat16* pa0 = A + (size_t)(bm + srow) * K + scol;
    const __hip_bfloat16* pa1 = A + (size_t)(bm + 64 + srow) * K + scol;
    const __hip_bfloat16* pb0 = Bw + (size_t)(bn + srow) * K + scol;
    const __hip_bfloat16* pb1 = Bw + (size_t)(bn + 64 + srow) * K + scol;
    char* At_b = (char*)&At[0][0] + wv * 1024;
    char* Bt_b = (char*)&Bt[0][0] + wv * 1024;

    for (int k0 = 0; k0 < K; k0 += 32) {
        gload_lds16(pa0 + k0, At_b);
        gload_lds16(pa1 + k0, At_b + 4096);
        gload_lds16(pb0 + k0, Bt_b);
        gload_lds16(pb1 + k0, Bt_b + 4096);
        __syncthreads();

        bf8_t af[4], bfr[4];
        #pragma unroll
        for (int mi = 0; mi < 4; ++mi)
            af[mi] = *(const bf8_t*)((const char*)&At[0][0] +
                     (wr * 64 + mi * 16 + (lane & 15)) * 64 + (lane >> 4) * 16);
        #pragma unroll
        for (int ni = 0; ni < 4; ++ni)
            bfr[ni] = *(const bf8_t*)((const char*)&Bt[0][0] +
                     (wc * 64 + ni * 16 + (lane & 15)) * 64 + (lane >> 4) * 16);
        #pragma unroll
        for (int mi = 0; mi < 4; ++mi)
            #pragma unroll
            for (int ni = 0; ni < 4; ++ni)
                acc[mi][ni] = __builtin_amdgcn_mfma_f32_16x16x32_bf16(
                    af[mi], bfr[ni], acc[mi][ni], 0, 0, 0);
        __syncthreads();
    }

    #pragma unroll
    for (int mi = 0; mi < 4; ++mi) {
        int r0 = bm + wr * 64 + mi * 16 + (lane >> 4) * 4;
        #pragma unroll
        for (int ni = 0; ni < 4; ++ni) {
            int c0 = bn + wc * 64 + ni * 16 + (lane & 15);
            #pragma unroll
            for (int j = 0; j < 4; ++j)
                Cout[(size_t)(r0 + j) * N + c0] = acc[mi][ni][j];
        }
    }
}

// ---------------------------------------------------------------------------
// Low-rank stage 1 (f32)
// ---------------------------------------------------------------------------
__global__ __launch_bounds__(256) void lr1_kernel(
    const float* __restrict__ X, const float* __restrict__ mixv,
    const float* __restrict__ M1, float* __restrict__ Hout,
    int D, int act, int Tlen)
{
    __shared__ float row[Cdim];
    __shared__ float red[256];
    int m = blockIdx.x;
    int tid = threadIdx.x;
    int t = m % Tlen;
    const float* xr = X + (size_t)m * Cdim;
    #pragma unroll
    for (int q = 0; q < 4; ++q) {
        int kq = tid + q * 256;
        float v = xr[kq];
        float pv = (t > 0) ? xr[kq - Cdim] : 0.f;
        row[kq] = v + (pv - v) * mixv[kq];
    }
    __syncthreads();
    int P = 256 / D;
    int p = tid / D, n = tid % D;
    int klen = Cdim / P;
    float acc = 0.f;
    int kend = (p + 1) * klen;
    for (int k = p * klen; k < kend; ++k)
        acc += row[k] * M1[(size_t)k * D + n];
    red[tid] = acc;
    __syncthreads();
    if (tid < D) {
        float s = 0.f;
        for (int q = 0; q < P; ++q) s += red[tid + q * D];
        if (act == 1) s = sigf(s);
        else if (act == 2) s = tanhf(s);
        Hout[(size_t)m * D + tid] = s;
    }
}

// ---------------------------------------------------------------------------
// Low-rank stage 2. act: 0 none, 1 sigmoid, 3 sigmoid*e^-0.5.
// ---------------------------------------------------------------------------
__global__ __launch_bounds__(256) void lr2_kernel(
    const float* __restrict__ Hin, const float* __restrict__ M2,
    const float* __restrict__ bias, float* __restrict__ OutF,
    __hip_bfloat16* __restrict__ OutB, int D, int act)
{
    __shared__ float hs[128];
    int m = blockIdx.y;
    int n = blockIdx.x * 256 + threadIdx.x;
    if (threadIdx.x < D) hs[threadIdx.x] = Hin[(size_t)m * D + threadIdx.x];
    __syncthreads();
    float acc = bias ? bias[n] : 0.f;
    for (int k = 0; k < D; ++k)
        acc += hs[k] * M2[(size_t)k * Cdim + n];
    if (act == 1) acc = sigf(acc);
    else if (act == 3) acc = sigf(acc) * 0.60653065971263342f;
    size_t oi = (size_t)m * Cdim + n;
    if (OutB) OutB[oi] = __float2bfloat16(acc);
    else OutF[oi] = acc;
}

// ---------------------------------------------------------------------------
// E1: kk-normalize -> aarr=-kkn, barr=kkn*at; ut; v_first passthrough.
// ---------------------------------------------------------------------------
__global__ __launch_bounds__(256) void e1_kernel(
    const float* __restrict__ kt, const __hip_bfloat16* __restrict__ at16,
    const float* __restrict__ rt, const float* __restrict__ vraw,
    const float* __restrict__ vt, const float* __restrict__ vfirst,
    const float* __restrict__ k_k, const float* __restrict__ k_a,
    const float* __restrict__ r_k,
    float* __restrict__ aarr, float* __restrict__ barr,
    float* __restrict__ ut, float* __restrict__ out2)
{
    int gid = blockIdx.x * 4 + (threadIdx.x >> 6);
    int lane = threadIdx.x & 63;
    int h = gid % Hdim;
    size_t idx = (size_t)gid * 64 + lane;
    int c = h * 64 + lane;
    float ktv = kt[idx];
    float atv = __bfloat162float(at16[idx]);
    float kk = ktv * k_k[c];
    float ss = wsum64(kk * kk);
    float norm = sqrtf(ss);
    float kkn = kk / fmaxf(norm, 1e-12f);
    aarr[idx] = -kkn;
    barr[idx] = kkn * atv;
    float kmix = ktv * (1.f + (atv - 1.f) * k_a[c]);
    float rv = rt[idx];
    float dot = wsum64(rv * kmix * r_k[c]);
    float vm = vraw[idx];
    float vf = vfirst[idx];
    vm = vm + (vf - vm) * vt[idx];
    ut[idx] = dot * vm;
    out2[idx] = vf;
}

// ---------------------------------------------------------------------------
// WKV scan v4: row-split ACROSS BLOCKS (4 blocks per (b,h), 16 rows each)
// + triple-buffered asm-batched loads (2 steps of lead).
// R7 analysis: 1 block/bh = 32 CUs, 88 VMEM instr/step/CU ~ 1400 cyc ->
// per-CU L1-throughput-bound. 4x split: 128 blocks x 128 thr (2 waves),
// ~350 cyc/step/CU. Lead 2 steps covers L2 latency. vmcnt(22): two newer
// sets (22 loads) stay in flight; oldest set + stores retire in order.
// ---------------------------------------------------------------------------
struct Ops { f4 a0, a1, d0, d1, k0, k1, b0, b1, r0, r1; float vi; };

static __device__ __forceinline__ void load_set(
    Ops& s, const float* pa, const float* pd, const float* pk,
    const float* pb, const float* pr, const float* pv)
{
    asm volatile(
        "global_load_dwordx4 %0, %11, off\n\t"
        "global_load_dwordx4 %1, %11, off offset:16\n\t"
        "global_load_dword   %10, %16, off\n\t"
        "global_load_dwordx4 %2, %12, off\n\t"
        "global_load_dwordx4 %3, %12, off offset:16\n\t"
        "global_load_dwordx4 %4, %13, off\n\t"
        "global_load_dwordx4 %5, %13, off offset:16\n\t"
        "global_load_dwordx4 %6, %14, off\n\t"
        "global_load_dwordx4 %7, %14, off offset:16\n\t"
        "global_load_dwordx4 %8, %15, off\n\t"
        "global_load_dwordx4 %9, %15, off offset:16"
        : "=&v"(s.a0), "=&v"(s.a1), "=&v"(s.d0), "=&v"(s.d1),
          "=&v"(s.k0), "=&v"(s.k1), "=&v"(s.b0), "=&v"(s.b1),
          "=&v"(s.r0), "=&v"(s.r1), "=&v"(s.vi)
        : "v"(pa), "v"(pd), "v"(pk), "v"(pb), "v"(pr), "v"(pv));
}

static __device__ __forceinline__ void wkv_wait22() {
    asm volatile("s_waitcnt vmcnt(22)" ::: "memory");
    __builtin_amdgcn_sched_barrier(0);
}

static __device__ __forceinline__ void wkv_compute(
    float S[8], const Ops& o, float* po, int q)
{
    float s0 = 0.f, s1 = 0.f, s2 = 0.f, s3 = 0.f;
    s0 = fmaf(S[0], o.a0.x, s0); s1 = fmaf(S[1], o.a0.y, s1);
    s2 = fmaf(S[2], o.a0.z, s2); s3 = fmaf(S[3], o.a0.w, s3);
    s0 = fmaf(S[4], o.a1.x, s0); s1 = fmaf(S[5], o.a1.y, s1);
    s2 = fmaf(S[6], o.a1.z, s2); s3 = fmaf(S[7], o.a1.w, s3);
    float sp = quad_reduce((s0 + s1) + (s2 + s3));
    sp += __shfl_xor(sp, 4);

    S[0] = fmaf(S[0], o.d0.x, fmaf(sp, o.b0.x, o.vi * o.k0.x));
    S[1] = fmaf(S[1], o.d0.y, fmaf(sp, o.b0.y, o.vi * o.k0.y));
    S[2] = fmaf(S[2], o.d0.z, fmaf(sp, o.b0.z, o.vi * o.k0.z));
    S[3] = fmaf(S[3], o.d0.w, fmaf(sp, o.b0.w, o.vi * o.k0.w));
    S[4] = fmaf(S[4], o.d1.x, fmaf(sp, o.b1.x, o.vi * o.k1.x));
    S[5] = fmaf(S[5], o.d1.y, fmaf(sp, o.b1.y, o.vi * o.k1.y));
    S[6] = fmaf(S[6], o.d1.z, fmaf(sp, o.b1.z, o.vi * o.k1.z));
    S[7] = fmaf(S[7], o.d1.w, fmaf(sp, o.b1.w, o.vi * o.k1.w));

    float o0 = S[0] * o.r0.x, o1 = S[1] * o.r0.y;
    float o2 = S[2] * o.r0.z, o3 = S[3] * o.r0.w;
    o0 = fmaf(S[4], o.r1.x, o0); o1 = fmaf(S[5], o.r1.y, o1);
    o2 = fmaf(S[6], o.r1.z, o2); o3 = fmaf(S[7], o.r1.w, o3);
    float op = quad_reduce((o0 + o1) + (o2 + o3));
    op += __shfl_xor(op, 4);
    if (q == 0) *po = op;
}

__global__ __launch_bounds__(128, 1) void wkv_kernel(
    const float* __restrict__ rt, const float* __restrict__ decay,
    const float* __restrict__ kt, const float* __restrict__ vt,
    const float* __restrict__ aarr, const float* __restrict__ barr,
    float* __restrict__ wkvt)
{
    int tid = threadIdx.x;
    int blk = blockIdx.x;              // 128 blocks: bh*4 + chunk
    int bh = blk >> 2, chunk = blk & 3;
    int b = bh >> 4, h = bh & 15;
    int i = chunk * 16 + (tid >> 3);   // state row owned by this 8-lane group
    int q = tid & 7;                   // column-slice owner (8 cols)
    int jb = q * 8;
    size_t base = ((size_t)b * Tdim) * Cdim + (size_t)h * Ndim;
    const float* pa = aarr + base + jb;
    const float* pd = decay + base + jb;
    const float* pk = kt + base + jb;
    const float* pb = barr + base + jb;
    const float* pr = rt + base + jb;
    const float* pv = vt + base + i;
    float* po = wkvt + base + i;

    float S[8];
    #pragma unroll
    for (int j = 0; j < 8; ++j) S[j] = 0.f;

    Ops A, B, C;
    load_set(A, pa, pd, pk, pb, pr, pv);
    {
        size_t o1 = (size_t)1 * Cdim, o2 = (size_t)2 * Cdim;
        load_set(B, pa + o1, pd + o1, pk + o1, pb + o1, pr + o1, pv + o1);
        load_set(C, pa + o2, pd + o2, pk + o2, pb + o2, pr + o2, pv + o2);
    }

    // 341 full iterations compute t = 0..1022; prefetch clamped to 1023.
    for (int t = 0; t < Tdim - 1; t += 3) {
        wkv_wait22();
        wkv_compute(S, A, po + (size_t)t * Cdim, q);
        size_t o3 = (size_t)((t + 3 < Tdim) ? t + 3 : Tdim - 1) * Cdim;
        load_set(A, pa + o3, pd + o3, pk + o3, pb + o3, pr + o3, pv + o3);

        wkv_wait22();
        wkv_compute(S, B, po + (size_t)(t + 1) * Cdim, q);
        size_t o4 = (size_t)((t + 4 < Tdim) ? t + 4 : Tdim - 1) * Cdim;
        load_set(B, pa + o4, pd + o4, pk + o4, pb + o4, pr + o4, pv + o4);

        wkv_wait22();
        wkv_compute(S, C, po + (size_t)(t + 2) * Cdim, q);
        size_t o5 = (size_t)((t + 5 < Tdim) ? t + 5 : Tdim - 1) * Cdim;
        load_set(C, pa + o5, pd + o5, pk + o5, pb + o5, pr + o5, pv + o5);
    }
    // epilogue: t = 1023 sits in A (loaded first of the last three)
    wkv_wait22();
    wkv_compute(S, A, po + (size_t)(Tdim - 1) * Cdim, q);
}

// ---------------------------------------------------------------------------
// E2: pt = GroupNorm(rt*wkvt)*ln_g + ln_b + ut; g16 = bf16(gt*pt)
// ---------------------------------------------------------------------------
__global__ __launch_bounds__(256) void e2_kernel(
    const float* __restrict__ rt, const float* __restrict__ wkvt,
    const float* __restrict__ ut, const __hip_bfloat16* __restrict__ gt16,
    const float* __restrict__ ln_g, const float* __restrict__ ln_b,
    __hip_bfloat16* __restrict__ g16)
{
    int gid = blockIdx.x * 4 + (threadIdx.x >> 6);
    int lane = threadIdx.x & 63;
    int h = gid % Hdim;
    size_t idx = (size_t)gid * 64 + lane;
    int c = h * 64 + lane;
    float x = rt[idx] * wkvt[idx];
    float mu = wsum64(x) * (1.f / 64.f);
    float d = x - mu;
    float var = wsum64(d * d) * (1.f / 64.f);
    float xn = d / sqrtf(var + EPS_GN);
    float pt = xn * ln_g[c] + ln_b[c] + ut[idx];
    float res = __bfloat162float(gt16[idx]) * pt;
    g16[idx] = __float2bfloat16(res);
}

// ---------------------------------------------------------------------------
extern "C" void kernel_launch(void* const* d_in, const int* in_sizes, int n_in,
                              void* d_out, int out_size, void* d_ws, size_t ws_size,
                              hipStream_t stream)
{
    (void)in_sizes; (void)n_in; (void)out_size; (void)ws_size;
    const float* xt      = (const float*)d_in[0];
    const float* v_first = (const float*)d_in[1];
    const float* tmix_r  = (const float*)d_in[2];
    const float* tmix_w  = (const float*)d_in[3];
    const float* tmix_k  = (const float*)d_in[4];
    const float* tmix_v  = (const float*)d_in[5];
    const float* tmix_a  = (const float*)d_in[6];
    const float* tmix_g  = (const float*)d_in[7];
    const float* w1 = (const float*)d_in[8];
    const float* w2 = (const float*)d_in[9];
    const float* w0 = (const float*)d_in[10];
    const float* a1 = (const float*)d_in[11];
    const float* a2 = (const float*)d_in[12];
    const float* a0 = (const float*)d_in[13];
    const float* v1 = (const float*)d_in[14];
    const float* v2 = (const float*)d_in[15];
    const float* v0 = (const float*)d_in[16];
    const float* g1 = (const float*)d_in[17];
    const float* g2 = (const float*)d_in[18];
    const float* k_k = (const float*)d_in[19];
    const float* k_a = (const float*)d_in[20];
    const float* r_k = (const float*)d_in[21];
    const float* W_r = (const float*)d_in[22];
    const float* W_k = (const float*)d_in[23];
    const float* W_v = (const float*)d_in[24];
    const float* W_o = (const float*)d_in[25];
    const float* ln_g = (const float*)d_in[26];
    const float* ln_b = (const float*)d_in[27];

    float* out = (float*)d_out;
    const size_t BTC = (size_t)Bdim * Tdim * Cdim;   // 2,097,152
    const int M = Bdim * Tdim;                        // 2048

    float* ws = (float*)d_ws;
    float* rt    = ws + 0 * BTC;
    float* kt    = ws + 1 * BTC;
    float* vraw  = ws + 2 * BTC;
    float* vt    = ws + 3 * BTC;
    float* decay = ws + 4 * BTC;
    float* aarr  = ws + 5 * BTC;
    float* barr  = ws + 6 * BTC;
    float* ut    = ws + 7 * BTC;
    float* wkv   = ws + 8 * BTC;
    __hip_bfloat16* bfa = (__hip_bfloat16*)(ws + 9 * BTC);
    __hip_bfloat16* at16 = bfa + 0 * BTC;
    __hip_bfloat16* gt16 = bfa + 1 * BTC;
    __hip_bfloat16* xr16 = bfa + 2 * BTC;
    __hip_bfloat16* xk16 = bfa + 3 * BTC;
    __hip_bfloat16* xv16 = bfa + 4 * BTC;   // reused as g16 after gemm_v
    __hip_bfloat16* Wb   = bfa + 5 * BTC;   // 4*CCdim = 2*BTC bf16
    float* hbuf = (float*)(bfa + 7 * BTC);
    __hip_bfloat16* g16 = xv16;

    // prep: weights + lerped activations -> bf16
    wconv_kernel<<<2048, 256, 0, stream>>>(W_r, W_k, W_v, W_o, Wb);
    prep_x<<<1024, 256, 0, stream>>>(xt, tmix_r, tmix_k, tmix_v, xr16, xk16, xv16);

    // big projections (bf16 MFMA)
    dim3 gg(Cdim / 128, M / 128);   // (8,16)
    gemm_mfma<<<gg, 256, 0, stream>>>(xr16, Wb + 0 * (size_t)CCdim, rt,   M, Cdim, Cdim);
    gemm_mfma<<<gg, 256, 0, stream>>>(xk16, Wb + 1 * (size_t)CCdim, kt,   M, Cdim, Cdim);
    gemm_mfma<<<gg, 256, 0, stream>>>(xv16, Wb + 2 * (size_t)CCdim, vraw, M, Cdim, Cdim);

    // low-rank paths
    lr1_kernel<<<M, 256, 0, stream>>>(xt, tmix_w, w1, hbuf, 64, 2, Tdim);
    lr2_kernel<<<dim3(Cdim / 256, M), 256, 0, stream>>>(hbuf, w2, w0, decay, nullptr, 64, 3);
    lr1_kernel<<<M, 256, 0, stream>>>(xt, tmix_a, a1, hbuf, 64, 0, Tdim);
    lr2_kernel<<<dim3(Cdim / 256, M), 256, 0, stream>>>(hbuf, a2, a0, nullptr, at16, 64, 1);
    lr1_kernel<<<M, 256, 0, stream>>>(xt, tmix_v, v1, hbuf, 32, 0, Tdim);
    lr2_kernel<<<dim3(Cdim / 256, M), 256, 0, stream>>>(hbuf, v2, v0, vt, nullptr, 32, 1);
    lr1_kernel<<<M, 256, 0, stream>>>(xt, tmix_g, g1, hbuf, 128, 1, Tdim);
    lr2_kernel<<<dim3(Cdim / 256, M), 256, 0, stream>>>(hbuf, g2, nullptr, nullptr, gt16, 128, 0);

    // E1
    e1_kernel<<<(Bdim * Tdim * Hdim) / 4, 256, 0, stream>>>(
        kt, at16, rt, vraw, vt, v_first, k_k, k_a, r_k,
        aarr, barr, ut, out + BTC);

    // WKV scan (4-way block split, triple-buffered reg pipeline)
    wkv_kernel<<<Bdim * Hdim * 4, 128, 0, stream>>>(rt, decay, kt, vt, aarr, barr, wkv);

    // E2 (writes bf16 gated output)
    e2_kernel<<<(Bdim * Tdim * Hdim) / 4, 256, 0, stream>>>(
        rt, wkv, ut, gt16, ln_g, ln_b, g16);

    // output projection (bf16 MFMA)
    gemm_mfma<<<gg, 256, 0, stream>>>(g16, Wb + 3 * (size_t)CCdim, out, M, Cdim, Cdim);
}

// Round 9
// 624.289 us; speedup vs baseline: 4.4085x; 1.2384x over previous
//
#include <hip/hip_runtime.h>
#include <hip/hip_bf16.h>
#include <math.h>

#define Bdim 2
#define Tdim 1024
#define Cdim 1024
#define Hdim 16
#define Ndim 64
#define CCdim (Cdim * Cdim)
#define EPS_GN 0.00064f

typedef __bf16 bf8_t __attribute__((ext_vector_type(8)));
typedef float f32x4 __attribute__((ext_vector_type(4)));
typedef float f4 __attribute__((ext_vector_type(4)));

static __device__ __forceinline__ float sigf(float x) { return 1.f / (1.f + expf(-x)); }

static __device__ __forceinline__ float wsum64(float v) {
    #pragma unroll
    for (int m = 1; m < 64; m <<= 1) v += __shfl_xor(v, m);
    return v;
}

static __device__ __forceinline__ void gload_lds16(const void* g, void* l) {
    __builtin_amdgcn_global_load_lds(
        (const __attribute__((address_space(1))) void*)g,
        (__attribute__((address_space(3))) void*)l, 16, 0, 0);
}

// quad (4-lane) reduce via DPP quad_perm: xor1 then xor2, VALU-speed.
static __device__ __forceinline__ float quad_reduce(float x) {
    int s1 = __builtin_amdgcn_update_dpp(0, __builtin_bit_cast(int, x),
                                         0xB1, 0xF, 0xF, true);   // [1,0,3,2]
    float y = x + __builtin_bit_cast(float, s1);
    int s2 = __builtin_amdgcn_update_dpp(0, __builtin_bit_cast(int, y),
                                         0x4E, 0xF, 0xF, true);   // [2,3,0,1]
    return y + __builtin_bit_cast(float, s2);
}

// ---------------------------------------------------------------------------
// Convert 4 weight matrices (C x C, row-major [n][k]) to bf16.
// ---------------------------------------------------------------------------
__global__ __launch_bounds__(256) void wconv_kernel(
    const float* __restrict__ W0, const float* __restrict__ W1,
    const float* __restrict__ W2, const float* __restrict__ W3,
    __hip_bfloat16* __restrict__ Wb)
{
    int blk = blockIdx.x;                 // 2048 blocks, 512 per matrix
    int which = blk >> 9;
    const float* src = (which == 0) ? W0 : (which == 1) ? W1 : (which == 2) ? W2 : W3;
    size_t e8 = ((size_t)(blk & 511) * 256 + threadIdx.x) * 8;
    float c[8];
    *(float4*)&c[0] = ((const float4*)(src + e8))[0];
    *(float4*)&c[4] = ((const float4*)(src + e8))[1];
    __hip_bfloat16 o[8];
    #pragma unroll
    for (int j = 0; j < 8; ++j) o[j] = __float2bfloat16(c[j]);
    __hip_bfloat16* dst = Wb + (size_t)which * CCdim + e8;
    ((ushort4*)dst)[0] = *(ushort4*)&o[0];
    ((ushort4*)dst)[1] = *(ushort4*)&o[4];
}

// ---------------------------------------------------------------------------
// Token-shift lerp for 3 mixes + bf16 convert: xr16, xk16, xv16.
// ---------------------------------------------------------------------------
__global__ __launch_bounds__(256) void prep_x(
    const float* __restrict__ xt,
    const float* __restrict__ mr, const float* __restrict__ mk, const float* __restrict__ mv,
    __hip_bfloat16* __restrict__ xr16, __hip_bfloat16* __restrict__ xk16,
    __hip_bfloat16* __restrict__ xv16)
{
    int idx8 = blockIdx.x * 256 + threadIdx.x;   // 0..262143
    int m = idx8 >> 7;
    int c8 = (idx8 & 127) * 8;
    int t = m & (Tdim - 1);
    const float* p = xt + (size_t)idx8 * 8;
    float cur[8], prv[8];
    *(float4*)&cur[0] = ((const float4*)p)[0];
    *(float4*)&cur[4] = ((const float4*)p)[1];
    if (t > 0) {
        *(float4*)&prv[0] = ((const float4*)(p - Cdim))[0];
        *(float4*)&prv[4] = ((const float4*)(p - Cdim))[1];
    } else {
        #pragma unroll
        for (int j = 0; j < 8; ++j) prv[j] = 0.f;
    }
    float mx[8];
    __hip_bfloat16 o[8];
    size_t ob = (size_t)idx8 * 8;

    *(float4*)&mx[0] = *(const float4*)(mr + c8);
    *(float4*)&mx[4] = *(const float4*)(mr + c8 + 4);
    #pragma unroll
    for (int j = 0; j < 8; ++j) o[j] = __float2bfloat16(cur[j] + (prv[j] - cur[j]) * mx[j]);
    ((ushort4*)(xr16 + ob))[0] = *(ushort4*)&o[0];
    ((ushort4*)(xr16 + ob))[1] = *(ushort4*)&o[4];

    *(float4*)&mx[0] = *(const float4*)(mk + c8);
    *(float4*)&mx[4] = *(const float4*)(mk + c8 + 4);
    #pragma unroll
    for (int j = 0; j < 8; ++j) o[j] = __float2bfloat16(cur[j] + (prv[j] - cur[j]) * mx[j]);
    ((ushort4*)(xk16 + ob))[0] = *(ushort4*)&o[0];
    ((ushort4*)(xk16 + ob))[1] = *(ushort4*)&o[4];

    *(float4*)&mx[0] = *(const float4*)(mv + c8);
    *(float4*)&mx[4] = *(const float4*)(mv + c8 + 4);
    #pragma unroll
    for (int j = 0; j < 8; ++j) o[j] = __float2bfloat16(cur[j] + (prv[j] - cur[j]) * mx[j]);
    ((ushort4*)(xv16 + ob))[0] = *(ushort4*)&o[0];
    ((ushort4*)(xv16 + ob))[1] = *(ushort4*)&o[4];
}

// ---------------------------------------------------------------------------
// Triple bf16 MFMA GEMM (z = 0,1,2 selects A/W/C): 128x128 tile, BK=32.
// 384 blocks -> full-chip occupancy vs 3 serial 128-block launches.
// ---------------------------------------------------------------------------
__global__ __launch_bounds__(256) void gemm3_mfma(
    const __hip_bfloat16* __restrict__ A0, const __hip_bfloat16* __restrict__ A1,
    const __hip_bfloat16* __restrict__ A2, const __hip_bfloat16* __restrict__ Wbase,
    float* __restrict__ C0, float* __restrict__ C1, float* __restrict__ C2)
{
    const int M = Bdim * Tdim, N = Cdim, K = Cdim;
    __shared__ unsigned short At[128][32];
    __shared__ unsigned short Bt[128][32];
    int z = blockIdx.z;
    const __hip_bfloat16* A = (z == 0) ? A0 : (z == 1) ? A1 : A2;
    const __hip_bfloat16* Bw = Wbase + (size_t)z * CCdim;
    float* Cout = (z == 0) ? C0 : (z == 1) ? C1 : C2;
    int tid = threadIdx.x;
    int lane = tid & 63, wv = tid >> 6;
    int bm = blockIdx.y * 128, bn = blockIdx.x * 128;
    int wr = wv >> 1, wc = wv & 1;

    f32x4 acc[4][4];
    #pragma unroll
    for (int mi = 0; mi < 4; ++mi)
        #pragma unroll
        for (int ni = 0; ni < 4; ++ni)
            acc[mi][ni] = (f32x4){0.f, 0.f, 0.f, 0.f};

    int srow = wv * 16 + (lane >> 2);
    int scol = (lane & 3) * 8;
    const __hip_bfloat16* pa0 = A + (size_t)(bm + srow) * K + scol;
    const __hip_bfloat16* pa1 = A + (size_t)(bm + 64 + srow) * K + scol;
    const __hip_bfloat16* pb0 = Bw + (size_t)(bn + srow) * K + scol;
    const __hip_bfloat16* pb1 = Bw + (size_t)(bn + 64 + srow) * K + scol;
    char* At_b = (char*)&At[0][0] + wv * 1024;
    char* Bt_b = (char*)&Bt[0][0] + wv * 1024;

    for (int k0 = 0; k0 < K; k0 += 32) {
        gload_lds16(pa0 + k0, At_b);
        gload_lds16(pa1 + k0, At_b + 4096);
        gload_lds16(pb0 + k0, Bt_b);
        gload_lds16(pb1 + k0, Bt_b + 4096);
        __syncthreads();

        bf8_t af[4], bfr[4];
        #pragma unroll
        for (int mi = 0; mi < 4; ++mi)
            af[mi] = *(const bf8_t*)((const char*)&At[0][0] +
                     (wr * 64 + mi * 16 + (lane & 15)) * 64 + (lane >> 4) * 16);
        #pragma unroll
        for (int ni = 0; ni < 4; ++ni)
            bfr[ni] = *(const bf8_t*)((const char*)&Bt[0][0] +
                     (wc * 64 + ni * 16 + (lane & 15)) * 64 + (lane >> 4) * 16);
        #pragma unroll
        for (int mi = 0; mi < 4; ++mi)
            #pragma unroll
            for (int ni = 0; ni < 4; ++ni)
                acc[mi][ni] = __builtin_amdgcn_mfma_f32_16x16x32_bf16(
                    af[mi], bfr[ni], acc[mi][ni], 0, 0, 0);
        __syncthreads();
    }

    #pragma unroll
    for (int mi = 0; mi < 4; ++mi) {
        int r0 = bm + wr * 64 + mi * 16 + (lane >> 4) * 4;
        #pragma unroll
        for (int ni = 0; ni < 4; ++ni) {
            int c0 = bn + wc * 64 + ni * 16 + (lane & 15);
            #pragma unroll
            for (int j = 0; j < 4; ++j)
                Cout[(size_t)(r0 + j) * N + c0] = acc[mi][ni][j];
        }
    }
}

// ---------------------------------------------------------------------------
// Single bf16 MFMA GEMM (output projection).
// ---------------------------------------------------------------------------
__global__ __launch_bounds__(256) void gemm_mfma(
    const __hip_bfloat16* __restrict__ A, const __hip_bfloat16* __restrict__ Bw,
    float* __restrict__ Cout, int M, int N, int K)
{
    __shared__ unsigned short At[128][32];
    __shared__ unsigned short Bt[128][32];
    int tid = threadIdx.x;
    int lane = tid & 63, wv = tid >> 6;
    int bm = blockIdx.y * 128, bn = blockIdx.x * 128;
    int wr = wv >> 1, wc = wv & 1;

    f32x4 acc[4][4];
    #pragma unroll
    for (int mi = 0; mi < 4; ++mi)
        #pragma unroll
        for (int ni = 0; ni < 4; ++ni)
            acc[mi][ni] = (f32x4){0.f, 0.f, 0.f, 0.f};

    int srow = wv * 16 + (lane >> 2);
    int scol = (lane & 3) * 8;
    const __hip_bfloat16* pa0 = A + (size_t)(bm + srow) * K + scol;
    const __hip_bfloat16* pa1 = A + (size_t)(bm + 64 + srow) * K + scol;
    const __hip_bfloat16* pb0 = Bw + (size_t)(bn + srow) * K + scol;
    const __hip_bfloat16* pb1 = Bw + (size_t)(bn + 64 + srow) * K + scol;
    char* At_b = (char*)&At[0][0] + wv * 1024;
    char* Bt_b = (char*)&Bt[0][0] + wv * 1024;

    for (int k0 = 0; k0 < K; k0 += 32) {
        gload_lds16(pa0 + k0, At_b);
        gload_lds16(pa1 + k0, At_b + 4096);
        gload_lds16(pb0 + k0, Bt_b);
        gload_lds16(pb1 + k0, Bt_b + 4096);
        __syncthreads();

        bf8_t af[4], bfr[4];
        #pragma unroll
        for (int mi = 0; mi < 4; ++mi)
            af[mi] = *(const bf8_t*)((const char*)&At[0][0] +
                     (wr * 64 + mi * 16 + (lane & 15)) * 64 + (lane >> 4) * 16);
        #pragma unroll
        for (int ni = 0; ni < 4; ++ni)
            bfr[ni] = *(const bf8_t*)((const char*)&Bt[0][0] +
                     (wc * 64 + ni * 16 + (lane & 15)) * 64 + (lane >> 4) * 16);
        #pragma unroll
        for (int mi = 0; mi < 4; ++mi)
            #pragma unroll
            for (int ni = 0; ni < 4; ++ni)
                acc[mi][ni] = __builtin_amdgcn_mfma_f32_16x16x32_bf16(
                    af[mi], bfr[ni], acc[mi][ni], 0, 0, 0);
        __syncthreads();
    }

    #pragma unroll
    for (int mi = 0; mi < 4; ++mi) {
        int r0 = bm + wr * 64 + mi * 16 + (lane >> 4) * 4;
        #pragma unroll
        for (int ni = 0; ni < 4; ++ni) {
            int c0 = bn + wc * 64 + ni * 16 + (lane & 15);
            #pragma unroll
            for (int j = 0; j < 4; ++j)
                Cout[(size_t)(r0 + j) * N + c0] = acc[mi][ni][j];
        }
    }
}

// ---------------------------------------------------------------------------
// Fused low-rank stage 1: all 4 paths (w,a,v,g), xt read ONCE per row.
// 4 lerped rows staged in LDS; per path the proven split-K dot + LDS reduce.
// ---------------------------------------------------------------------------
static __device__ __forceinline__ void lr1_dot(
    const float* row, float* red, const float* __restrict__ M1,
    int D, int act, float* __restrict__ out, int m, int tid)
{
    int P = 256 / D;
    int p = tid / D, n = tid % D;
    int klen = Cdim / P;
    float acc = 0.f;
    int kend = (p + 1) * klen;
    for (int k = p * klen; k < kend; ++k)
        acc += row[k] * M1[(size_t)k * D + n];
    red[tid] = acc;
    __syncthreads();
    if (tid < D) {
        float s = 0.f;
        for (int q = 0; q < P; ++q) s += red[tid + q * D];
        if (act == 1) s = sigf(s);
        else if (act == 2) s = tanhf(s);
        out[(size_t)m * D + tid] = s;
    }
    __syncthreads();
}

__global__ __launch_bounds__(256) void lr1_fused(
    const float* __restrict__ X,
    const float* __restrict__ mw, const float* __restrict__ ma,
    const float* __restrict__ mv, const float* __restrict__ mg,
    const float* __restrict__ w1, const float* __restrict__ a1,
    const float* __restrict__ v1, const float* __restrict__ g1,
    float* __restrict__ hw, float* __restrict__ ha,
    float* __restrict__ hv, float* __restrict__ hg)
{
    __shared__ float rw[Cdim], ra[Cdim], rv[Cdim], rg[Cdim];
    __shared__ float red[256];
    int m = blockIdx.x;
    int tid = threadIdx.x;
    int t = m & (Tdim - 1);
    const float* xr = X + (size_t)m * Cdim;
    #pragma unroll
    for (int q = 0; q < 4; ++q) {
        int k = tid + q * 256;
        float v = xr[k];
        float pv = (t > 0) ? xr[k - Cdim] : 0.f;
        float dlt = pv - v;
        rw[k] = v + dlt * mw[k];
        ra[k] = v + dlt * ma[k];
        rv[k] = v + dlt * mv[k];
        rg[k] = v + dlt * mg[k];
    }
    __syncthreads();
    lr1_dot(rw, red, w1, 64, 2, hw, m, tid);
    lr1_dot(ra, red, a1, 64, 0, ha, m, tid);
    lr1_dot(rv, red, v1, 32, 0, hv, m, tid);
    lr1_dot(rg, red, g1, 128, 1, hg, m, tid);
}

// ---------------------------------------------------------------------------
// Fused low-rank stage 2: all 4 expansions, per-path epilogue.
// grid (16, M): blockIdx.x>>2 = path, (blockIdx.x&3)*256+tid = n.
// ---------------------------------------------------------------------------
__global__ __launch_bounds__(256) void lr2_fused(
    const float* __restrict__ hw, const float* __restrict__ ha,
    const float* __restrict__ hv, const float* __restrict__ hg,
    const float* __restrict__ w2, const float* __restrict__ a2,
    const float* __restrict__ v2, const float* __restrict__ g2,
    const float* __restrict__ w0, const float* __restrict__ a0,
    const float* __restrict__ v0,
    float* __restrict__ decay, __hip_bfloat16* __restrict__ at16,
    float* __restrict__ vt, __hip_bfloat16* __restrict__ gt16)
{
    __shared__ float hs[128];
    int m = blockIdx.y;
    int path = blockIdx.x >> 2;
    int n = (blockIdx.x & 3) * 256 + threadIdx.x;
    const float* Hin; const float* M2; const float* bias; int D;
    if (path == 0)      { Hin = hw; M2 = w2; bias = w0; D = 64; }
    else if (path == 1) { Hin = ha; M2 = a2; bias = a0; D = 64; }
    else if (path == 2) { Hin = hv; M2 = v2; bias = v0; D = 32; }
    else                { Hin = hg; M2 = g2; bias = nullptr; D = 128; }
    if (threadIdx.x < D) hs[threadIdx.x] = Hin[(size_t)m * D + threadIdx.x];
    __syncthreads();
    float acc = bias ? bias[n] : 0.f;
    for (int k = 0; k < D; ++k)
        acc += hs[k] * M2[(size_t)k * Cdim + n];
    size_t oi = (size_t)m * Cdim + n;
    if (path == 0)      decay[oi] = sigf(acc) * 0.60653065971263342f;
    else if (path == 1) at16[oi] = __float2bfloat16(sigf(acc));
    else if (path == 2) vt[oi] = sigf(acc);
    else                gt16[oi] = __float2bfloat16(acc);
}

// ---------------------------------------------------------------------------
// E1: kk-normalize -> aarr=-kkn, barr=kkn*at; ut; v_first passthrough.
// ---------------------------------------------------------------------------
__global__ __launch_bounds__(256) void e1_kernel(
    const float* __restrict__ kt, const __hip_bfloat16* __restrict__ at16,
    const float* __restrict__ rt, const float* __restrict__ vraw,
    const float* __restrict__ vt, const float* __restrict__ vfirst,
    const float* __restrict__ k_k, const float* __restrict__ k_a,
    const float* __restrict__ r_k,
    float* __restrict__ aarr, float* __restrict__ barr,
    float* __restrict__ ut, float* __restrict__ out2)
{
    int gid = blockIdx.x * 4 + (threadIdx.x >> 6);
    int lane = threadIdx.x & 63;
    int h = gid % Hdim;
    size_t idx = (size_t)gid * 64 + lane;
    int c = h * 64 + lane;
    float ktv = kt[idx];
    float atv = __bfloat162float(at16[idx]);
    float kk = ktv * k_k[c];
    float ss = wsum64(kk * kk);
    float norm = sqrtf(ss);
    float kkn = kk / fmaxf(norm, 1e-12f);
    aarr[idx] = -kkn;
    barr[idx] = kkn * atv;
    float kmix = ktv * (1.f + (atv - 1.f) * k_a[c]);
    float rv = rt[idx];
    float dot = wsum64(rv * kmix * r_k[c]);
    float vm = vraw[idx];
    float vf = vfirst[idx];
    vm = vm + (vf - vm) * vt[idx];
    ut[idx] = dot * vm;
    out2[idx] = vf;
}

// ---------------------------------------------------------------------------
// WKV scan v5: 8-way block row-split (256 blocks x 64 thr, 8 rows each) +
// 4-deep asm-batched register pipeline (3 steps of lead).
// R8: 128 blocks, 22 VMEM instr/step/CU -> 600 cyc/step. Halve per-CU VMEM
// (11/step) and deepen lead (3 x ~180 = 530 cyc) to cover L2/HBM latency.
// Uniform s_waitcnt vmcnt(33): the 33 newest ops are exactly the 3 newer
// load-sets (stores interleave but only force-retire old, already-done
// loads); also exact after the 4-set prologue (44 outstanding -> 33 leaves
// B,C,D). 1024 % 4 == 0 -> clean 256-iteration loop, clamped tail loads.
// ---------------------------------------------------------------------------
struct Ops { f4 a0, a1, d0, d1, k0, k1, b0, b1, r0, r1; float vi; };

static __device__ __forceinline__ void load_set(
    Ops& s, const float* pa, const float* pd, const float* pk,
    const float* pb, const float* pr, const float* pv)
{
    asm volatile(
        "global_load_dwordx4 %0, %11, off\n\t"
        "global_load_dwordx4 %1, %11, off offset:16\n\t"
        "global_load_dword   %10, %16, off\n\t"
        "global_load_dwordx4 %2, %12, off\n\t"
        "global_load_dwordx4 %3, %12, off offset:16\n\t"
        "global_load_dwordx4 %4, %13, off\n\t"
        "global_load_dwordx4 %5, %13, off offset:16\n\t"
        "global_load_dwordx4 %6, %14, off\n\t"
        "global_load_dwordx4 %7, %14, off offset:16\n\t"
        "global_load_dwordx4 %8, %15, off\n\t"
        "global_load_dwordx4 %9, %15, off offset:16"
        : "=&v"(s.a0), "=&v"(s.a1), "=&v"(s.d0), "=&v"(s.d1),
          "=&v"(s.k0), "=&v"(s.k1), "=&v"(s.b0), "=&v"(s.b1),
          "=&v"(s.r0), "=&v"(s.r1), "=&v"(s.vi)
        : "v"(pa), "v"(pd), "v"(pk), "v"(pb), "v"(pr), "v"(pv));
}

static __device__ __forceinline__ void wkv_wait33() {
    asm volatile("s_waitcnt vmcnt(33)" ::: "memory");
    __builtin_amdgcn_sched_barrier(0);
}

static __device__ __forceinline__ void wkv_compute(
    float S[8], const Ops& o, float* po, int q)
{
    float s0 = 0.f, s1 = 0.f, s2 = 0.f, s3 = 0.f;
    s0 = fmaf(S[0], o.a0.x, s0); s1 = fmaf(S[1], o.a0.y, s1);
    s2 = fmaf(S[2], o.a0.z, s2); s3 = fmaf(S[3], o.a0.w, s3);
    s0 = fmaf(S[4], o.a1.x, s0); s1 = fmaf(S[5], o.a1.y, s1);
    s2 = fmaf(S[6], o.a1.z, s2); s3 = fmaf(S[7], o.a1.w, s3);
    float sp = quad_reduce((s0 + s1) + (s2 + s3));
    sp += __shfl_xor(sp, 4);

    S[0] = fmaf(S[0], o.d0.x, fmaf(sp, o.b0.x, o.vi * o.k0.x));
    S[1] = fmaf(S[1], o.d0.y, fmaf(sp, o.b0.y, o.vi * o.k0.y));
    S[2] = fmaf(S[2], o.d0.z, fmaf(sp, o.b0.z, o.vi * o.k0.z));
    S[3] = fmaf(S[3], o.d0.w, fmaf(sp, o.b0.w, o.vi * o.k0.w));
    S[4] = fmaf(S[4], o.d1.x, fmaf(sp, o.b1.x, o.vi * o.k1.x));
    S[5] = fmaf(S[5], o.d1.y, fmaf(sp, o.b1.y, o.vi * o.k1.y));
    S[6] = fmaf(S[6], o.d1.z, fmaf(sp, o.b1.z, o.vi * o.k1.z));
    S[7] = fmaf(S[7], o.d1.w, fmaf(sp, o.b1.w, o.vi * o.k1.w));

    float o0 = S[0] * o.r0.x, o1 = S[1] * o.r0.y;
    float o2 = S[2] * o.r0.z, o3 = S[3] * o.r0.w;
    o0 = fmaf(S[4], o.r1.x, o0); o1 = fmaf(S[5], o.r1.y, o1);
    o2 = fmaf(S[6], o.r1.z, o2); o3 = fmaf(S[7], o.r1.w, o3);
    float op = quad_reduce((o0 + o1) + (o2 + o3));
    op += __shfl_xor(op, 4);
    if (q == 0) *po = op;
}

__global__ __launch_bounds__(64, 1) void wkv_kernel(
    const float* __restrict__ rt, const float* __restrict__ decay,
    const float* __restrict__ kt, const float* __restrict__ vt,
    const float* __restrict__ aarr, const float* __restrict__ barr,
    float* __restrict__ wkvt)
{
    int tid = threadIdx.x;
    int blk = blockIdx.x;              // 256 blocks: bh*8 + chunk
    int bh = blk >> 3, chunk = blk & 7;
    int b = bh >> 4, h = bh & 15;
    int i = chunk * 8 + (tid >> 3);    // state row owned by this 8-lane group
    int q = tid & 7;                   // column-slice owner (8 cols)
    int jb = q * 8;
    size_t base = ((size_t)b * Tdim) * Cdim + (size_t)h * Ndim;
    const float* pa = aarr + base + jb;
    const float* pd = decay + base + jb;
    const float* pk = kt + base + jb;
    const float* pb = barr + base + jb;
    const float* pr = rt + base + jb;
    const float* pv = vt + base + i;
    float* po = wkvt + base + i;

    float S[8];
    #pragma unroll
    for (int j = 0; j < 8; ++j) S[j] = 0.f;

    Ops A, B, C, D;
    load_set(A, pa, pd, pk, pb, pr, pv);
    {
        size_t o1 = (size_t)1 * Cdim, o2 = (size_t)2 * Cdim, o3 = (size_t)3 * Cdim;
        load_set(B, pa + o1, pd + o1, pk + o1, pb + o1, pr + o1, pv + o1);
        load_set(C, pa + o2, pd + o2, pk + o2, pb + o2, pr + o2, pv + o2);
        load_set(D, pa + o3, pd + o3, pk + o3, pb + o3, pr + o3, pv + o3);
    }

    for (int t = 0; t < Tdim; t += 4) {
        wkv_wait33();
        wkv_compute(S, A, po + (size_t)t * Cdim, q);
        size_t o4 = (size_t)((t + 4 < Tdim) ? t + 4 : Tdim - 1) * Cdim;
        load_set(A, pa + o4, pd + o4, pk + o4, pb + o4, pr + o4, pv + o4);

        wkv_wait33();
        wkv_compute(S, B, po + (size_t)(t + 1) * Cdim, q);
        size_t o5 = (size_t)((t + 5 < Tdim) ? t + 5 : Tdim - 1) * Cdim;
        load_set(B, pa + o5, pd + o5, pk + o5, pb + o5, pr + o5, pv + o5);

        wkv_wait33();
        wkv_compute(S, C, po + (size_t)(t + 2) * Cdim, q);
        size_t o6 = (size_t)((t + 6 < Tdim) ? t + 6 : Tdim - 1) * Cdim;
        load_set(C, pa + o6, pd + o6, pk + o6, pb + o6, pr + o6, pv + o6);

        wkv_wait33();
        wkv_compute(S, D, po + (size_t)(t + 3) * Cdim, q);
        size_t o7 = (size_t)((t + 7 < Tdim) ? t + 7 : Tdim - 1) * Cdim;
        load_set(D, pa + o7, pd + o7, pk + o7, pb + o7, pr + o7, pv + o7);
    }
}

// ---------------------------------------------------------------------------
// E2: pt = GroupNorm(rt*wkvt)*ln_g + ln_b + ut; g16 = bf16(gt*pt)
// ---------------------------------------------------------------------------
__global__ __launch_bounds__(256) void e2_kernel(
    const float* __restrict__ rt, const float* __restrict__ wkvt,
    const float* __restrict__ ut, const __hip_bfloat16* __restrict__ gt16,
    const float* __restrict__ ln_g, const float* __restrict__ ln_b,
    __hip_bfloat16* __restrict__ g16)
{
    int gid = blockIdx.x * 4 + (threadIdx.x >> 6);
    int lane = threadIdx.x & 63;
    int h = gid % Hdim;
    size_t idx = (size_t)gid * 64 + lane;
    int c = h * 64 + lane;
    float x = rt[idx] * wkvt[idx];
    float mu = wsum64(x) * (1.f / 64.f);
    float d = x - mu;
    float var = wsum64(d * d) * (1.f / 64.f);
    float xn = d / sqrtf(var + EPS_GN);
    float pt = xn * ln_g[c] + ln_b[c] + ut[idx];
    float res = __bfloat162float(gt16[idx]) * pt;
    g16[idx] = __float2bfloat16(res);
}

// ---------------------------------------------------------------------------
extern "C" void kernel_launch(void* const* d_in, const int* in_sizes, int n_in,
                              void* d_out, int out_size, void* d_ws, size_t ws_size,
                              hipStream_t stream)
{
    (void)in_sizes; (void)n_in; (void)out_size; (void)ws_size;
    const float* xt      = (const float*)d_in[0];
    const float* v_first = (const float*)d_in[1];
    const float* tmix_r  = (const float*)d_in[2];
    const float* tmix_w  = (const float*)d_in[3];
    const float* tmix_k  = (const float*)d_in[4];
    const float* tmix_v  = (const float*)d_in[5];
    const float* tmix_a  = (const float*)d_in[6];
    const float* tmix_g  = (const float*)d_in[7];
    const float* w1 = (const float*)d_in[8];
    const float* w2 = (const float*)d_in[9];
    const float* w0 = (const float*)d_in[10];
    const float* a1 = (const float*)d_in[11];
    const float* a2 = (const float*)d_in[12];
    const float* a0 = (const float*)d_in[13];
    const float* v1 = (const float*)d_in[14];
    const float* v2 = (const float*)d_in[15];
    const float* v0 = (const float*)d_in[16];
    const float* g1 = (const float*)d_in[17];
    const float* g2 = (const float*)d_in[18];
    const float* k_k = (const float*)d_in[19];
    const float* k_a = (const float*)d_in[20];
    const float* r_k = (const float*)d_in[21];
    const float* W_r = (const float*)d_in[22];
    const float* W_k = (const float*)d_in[23];
    const float* W_v = (const float*)d_in[24];
    const float* W_o = (const float*)d_in[25];
    const float* ln_g = (const float*)d_in[26];
    const float* ln_b = (const float*)d_in[27];

    float* out = (float*)d_out;
    const size_t BTC = (size_t)Bdim * Tdim * Cdim;   // 2,097,152
    const int M = Bdim * Tdim;                        // 2048

    float* ws = (float*)d_ws;
    float* rt    = ws + 0 * BTC;
    float* kt    = ws + 1 * BTC;
    float* vraw  = ws + 2 * BTC;
    float* vt    = ws + 3 * BTC;
    float* decay = ws + 4 * BTC;
    float* aarr  = ws + 5 * BTC;
    float* barr  = ws + 6 * BTC;
    float* ut    = ws + 7 * BTC;
    float* wkv   = ws + 8 * BTC;
    __hip_bfloat16* bfa = (__hip_bfloat16*)(ws + 9 * BTC);
    __hip_bfloat16* at16 = bfa + 0 * BTC;
    __hip_bfloat16* gt16 = bfa + 1 * BTC;
    __hip_bfloat16* xr16 = bfa + 2 * BTC;
    __hip_bfloat16* xk16 = bfa + 3 * BTC;
    __hip_bfloat16* xv16 = bfa + 4 * BTC;   // reused as g16 after gemm_v
    __hip_bfloat16* Wb   = bfa + 5 * BTC;   // 4*CCdim = 2*BTC bf16
    float* hbuf = (float*)(bfa + 7 * BTC);  // 2048*288 f32 = 2.25 MB
    float* hw = hbuf;
    float* ha = hw + (size_t)M * 64;
    float* hv = ha + (size_t)M * 64;
    float* hg = hv + (size_t)M * 32;
    __hip_bfloat16* g16 = xv16;

    // prep: weights + lerped activations -> bf16
    wconv_kernel<<<2048, 256, 0, stream>>>(W_r, W_k, W_v, W_o, Wb);
    prep_x<<<1024, 256, 0, stream>>>(xt, tmix_r, tmix_k, tmix_v, xr16, xk16, xv16);

    // 3 big projections in one dispatch (384 blocks, full chip)
    dim3 gg3(Cdim / 128, M / 128, 3);
    gemm3_mfma<<<gg3, 256, 0, stream>>>(xr16, xk16, xv16, Wb, rt, kt, vraw);

    // fused low-rank chain (2 dispatches, xt read once)
    lr1_fused<<<M, 256, 0, stream>>>(xt, tmix_w, tmix_a, tmix_v, tmix_g,
                                     w1, a1, v1, g1, hw, ha, hv, hg);
    lr2_fused<<<dim3(16, M), 256, 0, stream>>>(hw, ha, hv, hg, w2, a2, v2, g2,
                                               w0, a0, v0, decay, at16, vt, gt16);

    // E1
    e1_kernel<<<(Bdim * Tdim * Hdim) / 4, 256, 0, stream>>>(
        kt, at16, rt, vraw, vt, v_first, k_k, k_a, r_k,
        aarr, barr, ut, out + BTC);

    // WKV scan (8-way block split, 4-deep reg pipeline)
    wkv_kernel<<<Bdim * Hdim * 8, 64, 0, stream>>>(rt, decay, kt, vt, aarr, barr, wkv);

    // E2 (writes bf16 gated output)
    e2_kernel<<<(Bdim * Tdim * Hdim) / 4, 256, 0, stream>>>(
        rt, wkv, ut, gt16, ln_g, ln_b, g16);

    // output projection (bf16 MFMA)
    dim3 gg(Cdim / 128, M / 128);
    gemm_mfma<<<gg, 256, 0, stream>>>(g16, Wb + 3 * (size_t)CCdim, out, M, Cdim, Cdim);
}

// Round 10
// 396.328 us; speedup vs baseline: 6.9441x; 1.5752x over previous
//
#include <hip/hip_runtime.h>
#include <hip/hip_bf16.h>
#include <math.h>

#define Bdim 2
#define Tdim 1024
#define Cdim 1024
#define Hdim 16
#define Ndim 64
#define CCdim (Cdim * Cdim)
#define EPS_GN 0.00064f

typedef __bf16 bf8_t __attribute__((ext_vector_type(8)));
typedef float f32x4 __attribute__((ext_vector_type(4)));
typedef float f4 __attribute__((ext_vector_type(4)));

static __device__ __forceinline__ float sigf(float x) { return 1.f / (1.f + expf(-x)); }

static __device__ __forceinline__ float wsum64(float v) {
    #pragma unroll
    for (int m = 1; m < 64; m <<= 1) v += __shfl_xor(v, m);
    return v;
}

static __device__ __forceinline__ void gload_lds16(const void* g, void* l) {
    __builtin_amdgcn_global_load_lds(
        (const __attribute__((address_space(1))) void*)g,
        (__attribute__((address_space(3))) void*)l, 16, 0, 0);
}

// quad (4-lane) reduce via DPP quad_perm: xor1 then xor2, VALU-speed.
static __device__ __forceinline__ float quad_reduce(float x) {
    int s1 = __builtin_amdgcn_update_dpp(0, __builtin_bit_cast(int, x),
                                         0xB1, 0xF, 0xF, true);   // [1,0,3,2]
    float y = x + __builtin_bit_cast(float, s1);
    int s2 = __builtin_amdgcn_update_dpp(0, __builtin_bit_cast(int, y),
                                         0x4E, 0xF, 0xF, true);   // [2,3,0,1]
    return y + __builtin_bit_cast(float, s2);
}

// ---------------------------------------------------------------------------
// prep_weights: 3 segments in one dispatch.
//  blk < 2048      : big W_r/W_k/W_v/W_o -> bf16 (wconv)
//  2048..2431      : build Wlr1[384][2048] = [diag(1-mix)M1 | diag(mix)M1]^T
//                    concat over paths {w,a,v,g}; rows 288..383 zeroed.
//  2432..6527      : build Wl2[4096][288] block-diag of M2_path^T.
// ---------------------------------------------------------------------------
__global__ __launch_bounds__(256) void prep_weights(
    const float* __restrict__ W0, const float* __restrict__ W1,
    const float* __restrict__ W2, const float* __restrict__ W3,
    const float* __restrict__ w1, const float* __restrict__ a1,
    const float* __restrict__ v1, const float* __restrict__ g1,
    const float* __restrict__ w2, const float* __restrict__ a2,
    const float* __restrict__ v2, const float* __restrict__ g2,
    const float* __restrict__ mw, const float* __restrict__ ma,
    const float* __restrict__ mv, const float* __restrict__ mg,
    __hip_bfloat16* __restrict__ Wb, __hip_bfloat16* __restrict__ Wlr1,
    __hip_bfloat16* __restrict__ Wl2)
{
    int blk = blockIdx.x;
    int tid = threadIdx.x;
    if (blk < 2048) {
        int which = blk >> 9;
        const float* src = (which == 0) ? W0 : (which == 1) ? W1 : (which == 2) ? W2 : W3;
        size_t e8 = ((size_t)(blk & 511) * 256 + tid) * 8;
        float c[8];
        *(float4*)&c[0] = ((const float4*)(src + e8))[0];
        *(float4*)&c[4] = ((const float4*)(src + e8))[1];
        __hip_bfloat16 o[8];
        #pragma unroll
        for (int j = 0; j < 8; ++j) o[j] = __float2bfloat16(c[j]);
        __hip_bfloat16* dst = Wb + (size_t)which * CCdim + e8;
        ((ushort4*)dst)[0] = *(ushort4*)&o[0];
        ((ushort4*)dst)[1] = *(ushort4*)&o[4];
    } else if (blk < 2432) {
        int n = blk - 2048;                 // 0..383
        if (n < 288) {
            const float* M1; const float* mix; int D, nl;
            if (n < 64)       { M1 = w1; mix = mw; D = 64;  nl = n; }
            else if (n < 128) { M1 = a1; mix = ma; D = 64;  nl = n - 64; }
            else if (n < 160) { M1 = v1; mix = mv; D = 32;  nl = n - 128; }
            else              { M1 = g1; mix = mg; D = 128; nl = n - 160; }
            #pragma unroll
            for (int i = 0; i < 8; ++i) {
                int kp = tid + i * 256;     // 0..2047
                int k = kp & 1023, half = kp >> 10;
                float mx = mix[k];
                float val = M1[(size_t)k * D + nl] * (half ? mx : 1.f - mx);
                Wlr1[(size_t)n * 2048 + kp] = __float2bfloat16(val);
            }
        } else {
            #pragma unroll
            for (int i = 0; i < 8; ++i)
                Wlr1[(size_t)n * 2048 + tid + i * 256] = __float2bfloat16(0.f);
        }
    } else {
        int np = blk - 2432;                // 0..4095
        int path = np >> 10, nl = np & 1023;
        const float* M2; int off, D;
        if (path == 0)      { M2 = w2; off = 0;   D = 64; }
        else if (path == 1) { M2 = a2; off = 64;  D = 64; }
        else if (path == 2) { M2 = v2; off = 128; D = 32; }
        else                { M2 = g2; off = 160; D = 128; }
        for (int kp = tid; kp < 288; kp += 256) {
            int kl = kp - off;
            float val = (kl >= 0 && kl < D) ? M2[(size_t)kl * Cdim + nl] : 0.f;
            Wl2[(size_t)np * 288 + kp] = __float2bfloat16(val);
        }
    }
}

// ---------------------------------------------------------------------------
// prep_all: token-shift lerps (r,k,v) -> bf16 + Aall = [x | xprev] bf16.
// ---------------------------------------------------------------------------
__global__ __launch_bounds__(256) void prep_all(
    const float* __restrict__ xt,
    const float* __restrict__ mr, const float* __restrict__ mk, const float* __restrict__ mv,
    __hip_bfloat16* __restrict__ xr16, __hip_bfloat16* __restrict__ xk16,
    __hip_bfloat16* __restrict__ xv16, __hip_bfloat16* __restrict__ Aall)
{
    int idx8 = blockIdx.x * 256 + threadIdx.x;   // 0..262143
    int m = idx8 >> 7;
    int c8 = (idx8 & 127) * 8;
    int t = m & (Tdim - 1);
    const float* p = xt + (size_t)idx8 * 8;
    float cur[8], prv[8];
    *(float4*)&cur[0] = ((const float4*)p)[0];
    *(float4*)&cur[4] = ((const float4*)p)[1];
    if (t > 0) {
        *(float4*)&prv[0] = ((const float4*)(p - Cdim))[0];
        *(float4*)&prv[4] = ((const float4*)(p - Cdim))[1];
    } else {
        #pragma unroll
        for (int j = 0; j < 8; ++j) prv[j] = 0.f;
    }
    float mx[8];
    __hip_bfloat16 o[8];
    size_t ob = (size_t)idx8 * 8;

    *(float4*)&mx[0] = *(const float4*)(mr + c8);
    *(float4*)&mx[4] = *(const float4*)(mr + c8 + 4);
    #pragma unroll
    for (int j = 0; j < 8; ++j) o[j] = __float2bfloat16(cur[j] + (prv[j] - cur[j]) * mx[j]);
    ((ushort4*)(xr16 + ob))[0] = *(ushort4*)&o[0];
    ((ushort4*)(xr16 + ob))[1] = *(ushort4*)&o[4];

    *(float4*)&mx[0] = *(const float4*)(mk + c8);
    *(float4*)&mx[4] = *(const float4*)(mk + c8 + 4);
    #pragma unroll
    for (int j = 0; j < 8; ++j) o[j] = __float2bfloat16(cur[j] + (prv[j] - cur[j]) * mx[j]);
    ((ushort4*)(xk16 + ob))[0] = *(ushort4*)&o[0];
    ((ushort4*)(xk16 + ob))[1] = *(ushort4*)&o[4];

    *(float4*)&mx[0] = *(const float4*)(mv + c8);
    *(float4*)&mx[4] = *(const float4*)(mv + c8 + 4);
    #pragma unroll
    for (int j = 0; j < 8; ++j) o[j] = __float2bfloat16(cur[j] + (prv[j] - cur[j]) * mx[j]);
    ((ushort4*)(xv16 + ob))[0] = *(ushort4*)&o[0];
    ((ushort4*)(xv16 + ob))[1] = *(ushort4*)&o[4];

    // Aall row m: [0,1024) = cur, [1024,2048) = prev (zeros at t=0)
    size_t ab = (size_t)m * 2048 + c8;
    #pragma unroll
    for (int j = 0; j < 8; ++j) o[j] = __float2bfloat16(cur[j]);
    ((ushort4*)(Aall + ab))[0] = *(ushort4*)&o[0];
    ((ushort4*)(Aall + ab))[1] = *(ushort4*)&o[4];
    #pragma unroll
    for (int j = 0; j < 8; ++j) o[j] = __float2bfloat16(prv[j]);
    ((ushort4*)(Aall + ab + 1024))[0] = *(ushort4*)&o[0];
    ((ushort4*)(Aall + ab + 1024))[1] = *(ushort4*)&o[4];
}

// ---------------------------------------------------------------------------
// Triple bf16 MFMA GEMM (z = 0,1,2 selects A/W/C): 128x128 tile, BK=32.
// ---------------------------------------------------------------------------
__global__ __launch_bounds__(256) void gemm3_mfma(
    const __hip_bfloat16* __restrict__ A0, const __hip_bfloat16* __restrict__ A1,
    const __hip_bfloat16* __restrict__ A2, const __hip_bfloat16* __restrict__ Wbase,
    float* __restrict__ C0, float* __restrict__ C1, float* __restrict__ C2)
{
    const int N = Cdim, K = Cdim;
    __shared__ unsigned short At[128][32];
    __shared__ unsigned short Bt[128][32];
    int z = blockIdx.z;
    const __hip_bfloat16* A = (z == 0) ? A0 : (z == 1) ? A1 : A2;
    const __hip_bfloat16* Bw = Wbase + (size_t)z * CCdim;
    float* Cout = (z == 0) ? C0 : (z == 1) ? C1 : C2;
    int tid = threadIdx.x;
    int lane = tid & 63, wv = tid >> 6;
    int bm = blockIdx.y * 128, bn = blockIdx.x * 128;
    int wr = wv >> 1, wc = wv & 1;

    f32x4 acc[4][4];
    #pragma unroll
    for (int mi = 0; mi < 4; ++mi)
        #pragma unroll
        for (int ni = 0; ni < 4; ++ni)
            acc[mi][ni] = (f32x4){0.f, 0.f, 0.f, 0.f};

    int srow = wv * 16 + (lane >> 2);
    int scol = (lane & 3) * 8;
    const __hip_bfloat16* pa0 = A + (size_t)(bm + srow) * K + scol;
    const __hip_bfloat16* pa1 = A + (size_t)(bm + 64 + srow) * K + scol;
    const __hip_bfloat16* pb0 = Bw + (size_t)(bn + srow) * K + scol;
    const __hip_bfloat16* pb1 = Bw + (size_t)(bn + 64 + srow) * K + scol;
    char* At_b = (char*)&At[0][0] + wv * 1024;
    char* Bt_b = (char*)&Bt[0][0] + wv * 1024;

    for (int k0 = 0; k0 < K; k0 += 32) {
        gload_lds16(pa0 + k0, At_b);
        gload_lds16(pa1 + k0, At_b + 4096);
        gload_lds16(pb0 + k0, Bt_b);
        gload_lds16(pb1 + k0, Bt_b + 4096);
        __syncthreads();

        bf8_t af[4], bfr[4];
        #pragma unroll
        for (int mi = 0; mi < 4; ++mi)
            af[mi] = *(const bf8_t*)((const char*)&At[0][0] +
                     (wr * 64 + mi * 16 + (lane & 15)) * 64 + (lane >> 4) * 16);
        #pragma unroll
        for (int ni = 0; ni < 4; ++ni)
            bfr[ni] = *(const bf8_t*)((const char*)&Bt[0][0] +
                     (wc * 64 + ni * 16 + (lane & 15)) * 64 + (lane >> 4) * 16);
        #pragma unroll
        for (int mi = 0; mi < 4; ++mi)
            #pragma unroll
            for (int ni = 0; ni < 4; ++ni)
                acc[mi][ni] = __builtin_amdgcn_mfma_f32_16x16x32_bf16(
                    af[mi], bfr[ni], acc[mi][ni], 0, 0, 0);
        __syncthreads();
    }

    #pragma unroll
    for (int mi = 0; mi < 4; ++mi) {
        int r0 = bm + wr * 64 + mi * 16 + (lane >> 4) * 4;
        #pragma unroll
        for (int ni = 0; ni < 4; ++ni) {
            int c0 = bn + wc * 64 + ni * 16 + (lane & 15);
            #pragma unroll
            for (int j = 0; j < 4; ++j)
                Cout[(size_t)(r0 + j) * N + c0] = acc[mi][ni][j];
        }
    }
}

// ---------------------------------------------------------------------------
// Single bf16 MFMA GEMM (output projection).
// ---------------------------------------------------------------------------
__global__ __launch_bounds__(256) void gemm_mfma(
    const __hip_bfloat16* __restrict__ A, const __hip_bfloat16* __restrict__ Bw,
    float* __restrict__ Cout, int M, int N, int K)
{
    __shared__ unsigned short At[128][32];
    __shared__ unsigned short Bt[128][32];
    int tid = threadIdx.x;
    int lane = tid & 63, wv = tid >> 6;
    int bm = blockIdx.y * 128, bn = blockIdx.x * 128;
    int wr = wv >> 1, wc = wv & 1;

    f32x4 acc[4][4];
    #pragma unroll
    for (int mi = 0; mi < 4; ++mi)
        #pragma unroll
        for (int ni = 0; ni < 4; ++ni)
            acc[mi][ni] = (f32x4){0.f, 0.f, 0.f, 0.f};

    int srow = wv * 16 + (lane >> 2);
    int scol = (lane & 3) * 8;
    const __hip_bfloat16* pa0 = A + (size_t)(bm + srow) * K + scol;
    const __hip_bfloat16* pa1 = A + (size_t)(bm + 64 + srow) * K + scol;
    const __hip_bfloat16* pb0 = Bw + (size_t)(bn + srow) * K + scol;
    const __hip_bfloat16* pb1 = Bw + (size_t)(bn + 64 + srow) * K + scol;
    char* At_b = (char*)&At[0][0] + wv * 1024;
    char* Bt_b = (char*)&Bt[0][0] + wv * 1024;

    for (int k0 = 0; k0 < K; k0 += 32) {
        gload_lds16(pa0 + k0, At_b);
        gload_lds16(pa1 + k0, At_b + 4096);
        gload_lds16(pb0 + k0, Bt_b);
        gload_lds16(pb1 + k0, Bt_b + 4096);
        __syncthreads();

        bf8_t af[4], bfr[4];
        #pragma unroll
        for (int mi = 0; mi < 4; ++mi)
            af[mi] = *(const bf8_t*)((const char*)&At[0][0] +
                     (wr * 64 + mi * 16 + (lane & 15)) * 64 + (lane >> 4) * 16);
        #pragma unroll
        for (int ni = 0; ni < 4; ++ni)
            bfr[ni] = *(const bf8_t*)((const char*)&Bt[0][0] +
                     (wc * 64 + ni * 16 + (lane & 15)) * 64 + (lane >> 4) * 16);
        #pragma unroll
        for (int mi = 0; mi < 4; ++mi)
            #pragma unroll
            for (int ni = 0; ni < 4; ++ni)
                acc[mi][ni] = __builtin_amdgcn_mfma_f32_16x16x32_bf16(
                    af[mi], bfr[ni], acc[mi][ni], 0, 0, 0);
        __syncthreads();
    }

    #pragma unroll
    for (int mi = 0; mi < 4; ++mi) {
        int r0 = bm + wr * 64 + mi * 16 + (lane >> 4) * 4;
        #pragma unroll
        for (int ni = 0; ni < 4; ++ni) {
            int c0 = bn + wc * 64 + ni * 16 + (lane & 15);
            #pragma unroll
            for (int j = 0; j < 4; ++j)
                Cout[(size_t)(r0 + j) * N + c0] = acc[mi][ni][j];
        }
    }
}

// ---------------------------------------------------------------------------
// gemm_lr1: H[2048][288] = Aall[2048][2048] @ Wlr1[384][2048]^T, bf16 out,
// per-column-range activation (tanh / none / sigmoid), skip n>=288.
// grid (3,16).
// ---------------------------------------------------------------------------
__global__ __launch_bounds__(256) void gemm_lr1(
    const __hip_bfloat16* __restrict__ A, const __hip_bfloat16* __restrict__ W,
    __hip_bfloat16* __restrict__ H)
{
    const int K = 2048;
    __shared__ unsigned short At[128][32];
    __shared__ unsigned short Bt[128][32];
    int tid = threadIdx.x;
    int lane = tid & 63, wv = tid >> 6;
    int bm = blockIdx.y * 128, bn = blockIdx.x * 128;
    int wr = wv >> 1, wc = wv & 1;

    f32x4 acc[4][4];
    #pragma unroll
    for (int mi = 0; mi < 4; ++mi)
        #pragma unroll
        for (int ni = 0; ni < 4; ++ni)
            acc[mi][ni] = (f32x4){0.f, 0.f, 0.f, 0.f};

    int srow = wv * 16 + (lane >> 2);
    int scol = (lane & 3) * 8;
    const __hip_bfloat16* pa0 = A + (size_t)(bm + srow) * K + scol;
    const __hip_bfloat16* pa1 = A + (size_t)(bm + 64 + srow) * K + scol;
    const __hip_bfloat16* pb0 = W + (size_t)(bn + srow) * K + scol;
    const __hip_bfloat16* pb1 = W + (size_t)(bn + 64 + srow) * K + scol;
    char* At_b = (char*)&At[0][0] + wv * 1024;
    char* Bt_b = (char*)&Bt[0][0] + wv * 1024;

    for (int k0 = 0; k0 < K; k0 += 32) {
        gload_lds16(pa0 + k0, At_b);
        gload_lds16(pa1 + k0, At_b + 4096);
        gload_lds16(pb0 + k0, Bt_b);
        gload_lds16(pb1 + k0, Bt_b + 4096);
        __syncthreads();

        bf8_t af[4], bfr[4];
        #pragma unroll
        for (int mi = 0; mi < 4; ++mi)
            af[mi] = *(const bf8_t*)((const char*)&At[0][0] +
                     (wr * 64 + mi * 16 + (lane & 15)) * 64 + (lane >> 4) * 16);
        #pragma unroll
        for (int ni = 0; ni < 4; ++ni)
            bfr[ni] = *(const bf8_t*)((const char*)&Bt[0][0] +
                     (wc * 64 + ni * 16 + (lane & 15)) * 64 + (lane >> 4) * 16);
        #pragma unroll
        for (int mi = 0; mi < 4; ++mi)
            #pragma unroll
            for (int ni = 0; ni < 4; ++ni)
                acc[mi][ni] = __builtin_amdgcn_mfma_f32_16x16x32_bf16(
                    af[mi], bfr[ni], acc[mi][ni], 0, 0, 0);
        __syncthreads();
    }

    #pragma unroll
    for (int mi = 0; mi < 4; ++mi) {
        int r0 = bm + wr * 64 + mi * 16 + (lane >> 4) * 4;
        #pragma unroll
        for (int ni = 0; ni < 4; ++ni) {
            int c0 = bn + wc * 64 + ni * 16 + (lane & 15);
            if (c0 < 288) {
                #pragma unroll
                for (int j = 0; j < 4; ++j) {
                    float v = acc[mi][ni][j];
                    if (c0 < 64) v = tanhf(v);
                    else if (c0 >= 160) v = sigf(v);
                    H[(size_t)(r0 + j) * 288 + c0] = __float2bfloat16(v);
                }
            }
        }
    }
}

// ---------------------------------------------------------------------------
// gemm_lr2: block-diag expansion. C[2048][4096] = H[2048][288] @ Wl2[4096][288]^T
// np>>10 selects path; epilogue adds bias + act, demuxes to 4 outputs.
// grid (32,16).
// ---------------------------------------------------------------------------
__global__ __launch_bounds__(256) void gemm_lr2(
    const __hip_bfloat16* __restrict__ H, const __hip_bfloat16* __restrict__ W,
    const float* __restrict__ w0, const float* __restrict__ a0,
    const float* __restrict__ v0,
    float* __restrict__ decay, __hip_bfloat16* __restrict__ at16,
    float* __restrict__ vt, __hip_bfloat16* __restrict__ gt16)
{
    const int K = 288;
    __shared__ unsigned short At[128][32];
    __shared__ unsigned short Bt[128][32];
    int tid = threadIdx.x;
    int lane = tid & 63, wv = tid >> 6;
    int bm = blockIdx.y * 128, bn = blockIdx.x * 128;
    int wr = wv >> 1, wc = wv & 1;

    f32x4 acc[4][4];
    #pragma unroll
    for (int mi = 0; mi < 4; ++mi)
        #pragma unroll
        for (int ni = 0; ni < 4; ++ni)
            acc[mi][ni] = (f32x4){0.f, 0.f, 0.f, 0.f};

    int srow = wv * 16 + (lane >> 2);
    int scol = (lane & 3) * 8;
    const __hip_bfloat16* pa0 = H + (size_t)(bm + srow) * K + scol;
    const __hip_bfloat16* pa1 = H + (size_t)(bm + 64 + srow) * K + scol;
    const __hip_bfloat16* pb0 = W + (size_t)(bn + srow) * K + scol;
    const __hip_bfloat16* pb1 = W + (size_t)(bn + 64 + srow) * K + scol;
    char* At_b = (char*)&At[0][0] + wv * 1024;
    char* Bt_b = (char*)&Bt[0][0] + wv * 1024;

    for (int k0 = 0; k0 < K; k0 += 32) {
        gload_lds16(pa0 + k0, At_b);
        gload_lds16(pa1 + k0, At_b + 4096);
        gload_lds16(pb0 + k0, Bt_b);
        gload_lds16(pb1 + k0, Bt_b + 4096);
        __syncthreads();

        bf8_t af[4], bfr[4];
        #pragma unroll
        for (int mi = 0; mi < 4; ++mi)
            af[mi] = *(const bf8_t*)((const char*)&At[0][0] +
                     (wr * 64 + mi * 16 + (lane & 15)) * 64 + (lane >> 4) * 16);
        #pragma unroll
        for (int ni = 0; ni < 4; ++ni)
            bfr[ni] = *(const bf8_t*)((const char*)&Bt[0][0] +
                     (wc * 64 + ni * 16 + (lane & 15)) * 64 + (lane >> 4) * 16);
        #pragma unroll
        for (int mi = 0; mi < 4; ++mi)
            #pragma unroll
            for (int ni = 0; ni < 4; ++ni)
                acc[mi][ni] = __builtin_amdgcn_mfma_f32_16x16x32_bf16(
                    af[mi], bfr[ni], acc[mi][ni], 0, 0, 0);
        __syncthreads();
    }

    #pragma unroll
    for (int mi = 0; mi < 4; ++mi) {
        int r0 = bm + wr * 64 + mi * 16 + (lane >> 4) * 4;
        #pragma unroll
        for (int ni = 0; ni < 4; ++ni) {
            int np = bn + wc * 64 + ni * 16 + (lane & 15);
            int path = np >> 10, nl = np & 1023;
            #pragma unroll
            for (int j = 0; j < 4; ++j) {
                float v = acc[mi][ni][j];
                size_t oi = (size_t)(r0 + j) * Cdim + nl;
                if (path == 0)      decay[oi] = sigf(v + w0[nl]) * 0.60653065971263342f;
                else if (path == 1) at16[oi] = __float2bfloat16(sigf(v + a0[nl]));
                else if (path == 2) vt[oi] = sigf(v + v0[nl]);
                else                gt16[oi] = __float2bfloat16(v);
            }
        }
    }
}

// ---------------------------------------------------------------------------
// E1: kk-normalize -> aarr=-kkn, barr=kkn*at; ut; v_first passthrough.
// ---------------------------------------------------------------------------
__global__ __launch_bounds__(256) void e1_kernel(
    const float* __restrict__ kt, const __hip_bfloat16* __restrict__ at16,
    const float* __restrict__ rt, const float* __restrict__ vraw,
    const float* __restrict__ vt, const float* __restrict__ vfirst,
    const float* __restrict__ k_k, const float* __restrict__ k_a,
    const float* __restrict__ r_k,
    float* __restrict__ aarr, float* __restrict__ barr,
    float* __restrict__ ut, float* __restrict__ out2)
{
    int gid = blockIdx.x * 4 + (threadIdx.x >> 6);
    int lane = threadIdx.x & 63;
    int h = gid % Hdim;
    size_t idx = (size_t)gid * 64 + lane;
    int c = h * 64 + lane;
    float ktv = kt[idx];
    float atv = __bfloat162float(at16[idx]);
    float kk = ktv * k_k[c];
    float ss = wsum64(kk * kk);
    float norm = sqrtf(ss);
    float kkn = kk / fmaxf(norm, 1e-12f);
    aarr[idx] = -kkn;
    barr[idx] = kkn * atv;
    float kmix = ktv * (1.f + (atv - 1.f) * k_a[c]);
    float rv = rt[idx];
    float dot = wsum64(rv * kmix * r_k[c]);
    float vm = vraw[idx];
    float vf = vfirst[idx];
    vm = vm + (vf - vm) * vt[idx];
    ut[idx] = dot * vm;
    out2[idx] = vf;
}

// ---------------------------------------------------------------------------
// WKV scan v5 (unchanged from R9): 8-way block row-split (256 blocks x 64
// thr) + 4-deep asm-batched register pipeline, counted vmcnt(33).
// ---------------------------------------------------------------------------
struct Ops { f4 a0, a1, d0, d1, k0, k1, b0, b1, r0, r1; float vi; };

static __device__ __forceinline__ void load_set(
    Ops& s, const float* pa, const float* pd, const float* pk,
    const float* pb, const float* pr, const float* pv)
{
    asm volatile(
        "global_load_dwordx4 %0, %11, off\n\t"
        "global_load_dwordx4 %1, %11, off offset:16\n\t"
        "global_load_dword   %10, %16, off\n\t"
        "global_load_dwordx4 %2, %12, off\n\t"
        "global_load_dwordx4 %3, %12, off offset:16\n\t"
        "global_load_dwordx4 %4, %13, off\n\t"
        "global_load_dwordx4 %5, %13, off offset:16\n\t"
        "global_load_dwordx4 %6, %14, off\n\t"
        "global_load_dwordx4 %7, %14, off offset:16\n\t"
        "global_load_dwordx4 %8, %15, off\n\t"
        "global_load_dwordx4 %9, %15, off offset:16"
        : "=&v"(s.a0), "=&v"(s.a1), "=&v"(s.d0), "=&v"(s.d1),
          "=&v"(s.k0), "=&v"(s.k1), "=&v"(s.b0), "=&v"(s.b1),
          "=&v"(s.r0), "=&v"(s.r1), "=&v"(s.vi)
        : "v"(pa), "v"(pd), "v"(pk), "v"(pb), "v"(pr), "v"(pv));
}

static __device__ __forceinline__ void wkv_wait33() {
    asm volatile("s_waitcnt vmcnt(33)" ::: "memory");
    __builtin_amdgcn_sched_barrier(0);
}

static __device__ __forceinline__ void wkv_compute(
    float S[8], const Ops& o, float* po, int q)
{
    float s0 = 0.f, s1 = 0.f, s2 = 0.f, s3 = 0.f;
    s0 = fmaf(S[0], o.a0.x, s0); s1 = fmaf(S[1], o.a0.y, s1);
    s2 = fmaf(S[2], o.a0.z, s2); s3 = fmaf(S[3], o.a0.w, s3);
    s0 = fmaf(S[4], o.a1.x, s0); s1 = fmaf(S[5], o.a1.y, s1);
    s2 = fmaf(S[6], o.a1.z, s2); s3 = fmaf(S[7], o.a1.w, s3);
    float sp = quad_reduce((s0 + s1) + (s2 + s3));
    sp += __shfl_xor(sp, 4);

    S[0] = fmaf(S[0], o.d0.x, fmaf(sp, o.b0.x, o.vi * o.k0.x));
    S[1] = fmaf(S[1], o.d0.y, fmaf(sp, o.b0.y, o.vi * o.k0.y));
    S[2] = fmaf(S[2], o.d0.z, fmaf(sp, o.b0.z, o.vi * o.k0.z));
    S[3] = fmaf(S[3], o.d0.w, fmaf(sp, o.b0.w, o.vi * o.k0.w));
    S[4] = fmaf(S[4], o.d1.x, fmaf(sp, o.b1.x, o.vi * o.k1.x));
    S[5] = fmaf(S[5], o.d1.y, fmaf(sp, o.b1.y, o.vi * o.k1.y));
    S[6] = fmaf(S[6], o.d1.z, fmaf(sp, o.b1.z, o.vi * o.k1.z));
    S[7] = fmaf(S[7], o.d1.w, fmaf(sp, o.b1.w, o.vi * o.k1.w));

    float o0 = S[0] * o.r0.x, o1 = S[1] * o.r0.y;
    float o2 = S[2] * o.r0.z, o3 = S[3] * o.r0.w;
    o0 = fmaf(S[4], o.r1.x, o0); o1 = fmaf(S[5], o.r1.y, o1);
    o2 = fmaf(S[6], o.r1.z, o2); o3 = fmaf(S[7], o.r1.w, o3);
    float op = quad_reduce((o0 + o1) + (o2 + o3));
    op += __shfl_xor(op, 4);
    if (q == 0) *po = op;
}

__global__ __launch_bounds__(64, 1) void wkv_kernel(
    const float* __restrict__ rt, const float* __restrict__ decay,
    const float* __restrict__ kt, const float* __restrict__ vt,
    const float* __restrict__ aarr, const float* __restrict__ barr,
    float* __restrict__ wkvt)
{
    int tid = threadIdx.x;
    int blk = blockIdx.x;              // 256 blocks: bh*8 + chunk
    int bh = blk >> 3, chunk = blk & 7;
    int b = bh >> 4, h = bh & 15;
    int i = chunk * 8 + (tid >> 3);    // state row owned by this 8-lane group
    int q = tid & 7;                   // column-slice owner (8 cols)
    int jb = q * 8;
    size_t base = ((size_t)b * Tdim) * Cdim + (size_t)h * Ndim;
    const float* pa = aarr + base + jb;
    const float* pd = decay + base + jb;
    const float* pk = kt + base + jb;
    const float* pb = barr + base + jb;
    const float* pr = rt + base + jb;
    const float* pv = vt + base + i;
    float* po = wkvt + base + i;

    float S[8];
    #pragma unroll
    for (int j = 0; j < 8; ++j) S[j] = 0.f;

    Ops A, B, C, D;
    load_set(A, pa, pd, pk, pb, pr, pv);
    {
        size_t o1 = (size_t)1 * Cdim, o2 = (size_t)2 * Cdim, o3 = (size_t)3 * Cdim;
        load_set(B, pa + o1, pd + o1, pk + o1, pb + o1, pr + o1, pv + o1);
        load_set(C, pa + o2, pd + o2, pk + o2, pb + o2, pr + o2, pv + o2);
        load_set(D, pa + o3, pd + o3, pk + o3, pb + o3, pr + o3, pv + o3);
    }

    for (int t = 0; t < Tdim; t += 4) {
        wkv_wait33();
        wkv_compute(S, A, po + (size_t)t * Cdim, q);
        size_t o4 = (size_t)((t + 4 < Tdim) ? t + 4 : Tdim - 1) * Cdim;
        load_set(A, pa + o4, pd + o4, pk + o4, pb + o4, pr + o4, pv + o4);

        wkv_wait33();
        wkv_compute(S, B, po + (size_t)(t + 1) * Cdim, q);
        size_t o5 = (size_t)((t + 5 < Tdim) ? t + 5 : Tdim - 1) * Cdim;
        load_set(B, pa + o5, pd + o5, pk + o5, pb + o5, pr + o5, pv + o5);

        wkv_wait33();
        wkv_compute(S, C, po + (size_t)(t + 2) * Cdim, q);
        size_t o6 = (size_t)((t + 6 < Tdim) ? t + 6 : Tdim - 1) * Cdim;
        load_set(C, pa + o6, pd + o6, pk + o6, pb + o6, pr + o6, pv + o6);

        wkv_wait33();
        wkv_compute(S, D, po + (size_t)(t + 3) * Cdim, q);
        size_t o7 = (size_t)((t + 7 < Tdim) ? t + 7 : Tdim - 1) * Cdim;
        load_set(D, pa + o7, pd + o7, pk + o7, pb + o7, pr + o7, pv + o7);
    }
}

// ---------------------------------------------------------------------------
// E2: pt = GroupNorm(rt*wkvt)*ln_g + ln_b + ut; g16 = bf16(gt*pt)
// ---------------------------------------------------------------------------
__global__ __launch_bounds__(256) void e2_kernel(
    const float* __restrict__ rt, const float* __restrict__ wkvt,
    const float* __restrict__ ut, const __hip_bfloat16* __restrict__ gt16,
    const float* __restrict__ ln_g, const float* __restrict__ ln_b,
    __hip_bfloat16* __restrict__ g16)
{
    int gid = blockIdx.x * 4 + (threadIdx.x >> 6);
    int lane = threadIdx.x & 63;
    int h = gid % Hdim;
    size_t idx = (size_t)gid * 64 + lane;
    int c = h * 64 + lane;
    float x = rt[idx] * wkvt[idx];
    float mu = wsum64(x) * (1.f / 64.f);
    float d = x - mu;
    float var = wsum64(d * d) * (1.f / 64.f);
    float xn = d / sqrtf(var + EPS_GN);
    float pt = xn * ln_g[c] + ln_b[c] + ut[idx];
    float res = __bfloat162float(gt16[idx]) * pt;
    g16[idx] = __float2bfloat16(res);
}

// ---------------------------------------------------------------------------
extern "C" void kernel_launch(void* const* d_in, const int* in_sizes, int n_in,
                              void* d_out, int out_size, void* d_ws, size_t ws_size,
                              hipStream_t stream)
{
    (void)in_sizes; (void)n_in; (void)out_size; (void)ws_size;
    const float* xt      = (const float*)d_in[0];
    const float* v_first = (const float*)d_in[1];
    const float* tmix_r  = (const float*)d_in[2];
    const float* tmix_w  = (const float*)d_in[3];
    const float* tmix_k  = (const float*)d_in[4];
    const float* tmix_v  = (const float*)d_in[5];
    const float* tmix_a  = (const float*)d_in[6];
    const float* tmix_g  = (const float*)d_in[7];
    const float* w1 = (const float*)d_in[8];
    const float* w2 = (const float*)d_in[9];
    const float* w0 = (const float*)d_in[10];
    const float* a1 = (const float*)d_in[11];
    const float* a2 = (const float*)d_in[12];
    const float* a0 = (const float*)d_in[13];
    const float* v1 = (const float*)d_in[14];
    const float* v2 = (const float*)d_in[15];
    const float* v0 = (const float*)d_in[16];
    const float* g1 = (const float*)d_in[17];
    const float* g2 = (const float*)d_in[18];
    const float* k_k = (const float*)d_in[19];
    const float* k_a = (const float*)d_in[20];
    const float* r_k = (const float*)d_in[21];
    const float* W_r = (const float*)d_in[22];
    const float* W_k = (const float*)d_in[23];
    const float* W_v = (const float*)d_in[24];
    const float* W_o = (const float*)d_in[25];
    const float* ln_g = (const float*)d_in[26];
    const float* ln_b = (const float*)d_in[27];

    float* out = (float*)d_out;
    const size_t BTC = (size_t)Bdim * Tdim * Cdim;   // 2,097,152
    const int M = Bdim * Tdim;                        // 2048

    float* ws = (float*)d_ws;
    float* rt    = ws + 0 * BTC;
    float* kt    = ws + 1 * BTC;
    float* vraw  = ws + 2 * BTC;
    float* vt    = ws + 3 * BTC;
    float* decay = ws + 4 * BTC;
    float* aarr  = ws + 5 * BTC;
    float* barr  = ws + 6 * BTC;
    float* ut    = ws + 7 * BTC;
    float* wkv   = ws + 8 * BTC;
    __hip_bfloat16* bfa = (__hip_bfloat16*)(ws + 9 * BTC);
    __hip_bfloat16* at16 = bfa + 0 * BTC;
    __hip_bfloat16* gt16 = bfa + 1 * BTC;
    __hip_bfloat16* xr16 = bfa + 2 * BTC;
    __hip_bfloat16* xk16 = bfa + 3 * BTC;
    __hip_bfloat16* xv16 = bfa + 4 * BTC;   // reused as g16 after gemm3
    __hip_bfloat16* Wb   = bfa + 5 * BTC;   // 4*CCdim = 2*BTC bf16
    // Aliased scratch (dead before their slots' writers run):
    __hip_bfloat16* Aall = (__hip_bfloat16*)decay;           // 2048x2048 bf16 = 8MB (decay written later by gemm_lr2)
    __hip_bfloat16* Wlr1 = (__hip_bfloat16*)aarr;            // 384x2048 (aarr written later by e1)
    __hip_bfloat16* Wl2  = Wlr1 + (size_t)384 * 2048;        // 4096x288
    __hip_bfloat16* hcat = Wl2 + (size_t)4096 * 288;         // 2048x288 (total 4.9MB < 8MB slot)
    __hip_bfloat16* g16 = xv16;

    // weight prep: big W -> bf16, Wlr1, Wl2 (one dispatch, 3 segments)
    prep_weights<<<6528, 256, 0, stream>>>(
        W_r, W_k, W_v, W_o, w1, a1, v1, g1, w2, a2, v2, g2,
        tmix_w, tmix_a, tmix_v, tmix_g, Wb, Wlr1, Wl2);

    // activation prep: 3 lerps -> bf16, Aall = [x | xprev] bf16
    prep_all<<<1024, 256, 0, stream>>>(xt, tmix_r, tmix_k, tmix_v,
                                       xr16, xk16, xv16, Aall);

    // low-rank chain as 2 MFMA GEMMs
    gemm_lr1<<<dim3(3, 16), 256, 0, stream>>>(Aall, Wlr1, hcat);
    gemm_lr2<<<dim3(32, 16), 256, 0, stream>>>(hcat, Wl2, w0, a0, v0,
                                               decay, at16, vt, gt16);

    // 3 big projections in one dispatch (384 blocks, full chip)
    dim3 gg3(Cdim / 128, M / 128, 3);
    gemm3_mfma<<<gg3, 256, 0, stream>>>(xr16, xk16, xv16, Wb, rt, kt, vraw);

    // E1
    e1_kernel<<<(Bdim * Tdim * Hdim) / 4, 256, 0, stream>>>(
        kt, at16, rt, vraw, vt, v_first, k_k, k_a, r_k,
        aarr, barr, ut, out + BTC);

    // WKV scan (8-way block split, 4-deep reg pipeline)
    wkv_kernel<<<Bdim * Hdim * 8, 64, 0, stream>>>(rt, decay, kt, vt, aarr, barr, wkv);

    // E2 (writes bf16 gated output)
    e2_kernel<<<(Bdim * Tdim * Hdim) / 4, 256, 0, stream>>>(
        rt, wkv, ut, gt16, ln_g, ln_b, g16);

    // output projection (bf16 MFMA)
    dim3 gg(Cdim / 128, M / 128);
    gemm_mfma<<<gg, 256, 0, stream>>>(g16, Wb + 3 * (size_t)CCdim, out, M, Cdim, Cdim);
}